// Round 5
// baseline (341.972 us; speedup 1.0000x reference)
//
#include <hip/hip_runtime.h>
#include <stdint.h>
#include <math.h>

#define TOK 2048
#define DMODEL 4096
#define QKV_LD 5120   // q(4096) | k(1024); V goes transposed to vtg
#define KVB 64
#define PS_LD 72      // 64 kv + 8 pad (P-tile LDS stride)

typedef __attribute__((ext_vector_type(8))) short short8;
typedef __attribute__((ext_vector_type(4))) short short4v;
typedef __attribute__((ext_vector_type(8))) __bf16 bf16x8;
typedef __attribute__((ext_vector_type(4))) float f32x4;

__device__ __forceinline__ unsigned short f2bf(float f) {
  unsigned u = __float_as_uint(f);
  u += 0x7fffu + ((u >> 16) & 1u);   // RNE
  return (unsigned short)(u >> 16);
}

__device__ __forceinline__ void gl16(const void* g, void* l) {
  __builtin_amdgcn_global_load_lds((__attribute__((address_space(1))) void*)g,
                                   (__attribute__((address_space(3))) void*)l,
                                   16, 0, 0);
}

__device__ __forceinline__ f32x4 mfma16(short8 a, short8 b, f32x4 c) {
  return __builtin_amdgcn_mfma_f32_16x16x32_bf16(__builtin_bit_cast(bf16x8, a),
                                                 __builtin_bit_cast(bf16x8, b),
                                                 c, 0, 0, 0);
}

__device__ __forceinline__ float fexp2(float x) {
  float r;
  asm("v_exp_f32 %0, %1" : "=v"(r) : "v"(x));
  return r;
}

template <int N>
__device__ __forceinline__ void waitvm() {
  if constexpr (N == 0) asm volatile("s_waitcnt vmcnt(0)" ::: "memory");
  else if constexpr (N == 6) asm volatile("s_waitcnt vmcnt(6)" ::: "memory");
  else if constexpr (N == 7) asm volatile("s_waitcnt vmcnt(7)" ::: "memory");
  else static_assert(N == 0 || N == 6 || N == 7, "add literal");
}

// ---------------- RMSNorm: fp32 x -> bf16 h ----------------
__global__ __launch_bounds__(256) void k_rmsnorm(const float* __restrict__ x,
                                                 const float* __restrict__ w,
                                                 unsigned short* __restrict__ h) {
  const int row = blockIdx.x;
  const float* xr = x + (size_t)row * DMODEL;
  float4 v[4];
  float ss = 0.f;
#pragma unroll
  for (int i = 0; i < 4; ++i) {
    v[i] = *(const float4*)(xr + threadIdx.x * 4 + i * 1024);
    ss += v[i].x * v[i].x + v[i].y * v[i].y + v[i].z * v[i].z + v[i].w * v[i].w;
  }
#pragma unroll
  for (int m = 1; m < 64; m <<= 1) ss += __shfl_xor(ss, m, 64);
  __shared__ float ws4[4];
  if ((threadIdx.x & 63) == 0) ws4[threadIdx.x >> 6] = ss;
  __syncthreads();
  const float scale = rsqrtf((ws4[0] + ws4[1] + ws4[2] + ws4[3]) * (1.0f / DMODEL) + 1e-5f);
  unsigned short* hr = h + (size_t)row * DMODEL;
#pragma unroll
  for (int i = 0; i < 4; ++i) {
    int col = threadIdx.x * 4 + i * 1024;
    float4 wv = *(const float4*)(w + col);
    uint2 o;
    o.x = (unsigned)f2bf(v[i].x * scale * wv.x) | ((unsigned)f2bf(v[i].y * scale * wv.y) << 16);
    o.y = (unsigned)f2bf(v[i].z * scale * wv.z) | ((unsigned)f2bf(v[i].w * scale * wv.w) << 16);
    *(uint2*)(hr + col) = o;
  }
}

// ------- Weight convert+transpose: W[K][N] fp32 -> WT[N][K] bf16 -------
__global__ __launch_bounds__(256) void k_wconvert(const float* __restrict__ W,
                                                  unsigned short* __restrict__ WT,
                                                  int K, int N) {
  __shared__ unsigned short tile[64][65];
  const int n0 = blockIdx.x * 64, k0 = blockIdx.y * 64;
  const int t = threadIdx.x;
  {
    const int r = t >> 2, c0 = (t & 3) * 16;
    const float* src = W + (size_t)(k0 + r) * N + n0 + c0;
#pragma unroll
    for (int i = 0; i < 4; ++i) {
      float4 f = *(const float4*)(src + i * 4);
      tile[r][c0 + i * 4 + 0] = f2bf(f.x);
      tile[r][c0 + i * 4 + 1] = f2bf(f.y);
      tile[r][c0 + i * 4 + 2] = f2bf(f.z);
      tile[r][c0 + i * 4 + 3] = f2bf(f.w);
    }
  }
  __syncthreads();
  {
    const int n = t >> 2, c0 = (t & 3) * 16;
    unsigned short* dst = WT + (size_t)(n0 + n) * K + k0 + c0;
    unsigned short v[16];
#pragma unroll
    for (int i = 0; i < 16; ++i) v[i] = tile[c0 + i][n];
    uint4 o0, o1;
    o0.x = v[0] | ((unsigned)v[1] << 16);  o0.y = v[2] | ((unsigned)v[3] << 16);
    o0.z = v[4] | ((unsigned)v[5] << 16);  o0.w = v[6] | ((unsigned)v[7] << 16);
    o1.x = v[8] | ((unsigned)v[9] << 16);  o1.y = v[10] | ((unsigned)v[11] << 16);
    o1.z = v[12] | ((unsigned)v[13] << 16); o1.w = v[14] | ((unsigned)v[15] << 16);
    *(uint4*)dst = o0;
    *(uint4*)(dst + 8) = o1;
  }
}

// ======== Counted-vmcnt pipelined GEMM: A[M][K] x BT[N][K] -> C[M][N] ========
// 8 waves (2M x 4N), BK=64, double-buffered LDS, XOR-swizzled tiles.
// Next-tile global_load_lds stays in flight across raw s_barrier; only a
// counted vmcnt(LOADS) wait per K-tile (never a drain until the last tile).
__device__ __forceinline__ short8 rdfrag(const unsigned short* buf, int row, int kc) {
  return *(const short8*)((const char*)buf + row * 128 + ((kc ^ (row & 7)) << 4));
}

template <int BM, int BN>
__device__ __forceinline__ void stage_tile(const unsigned short* __restrict__ A,
                                           const unsigned short* __restrict__ BT,
                                           unsigned short* __restrict__ buf,
                                           int m0, int n0, int K, int kt, int tid) {
  constexpr int ALOADS = BM * 8 / 512;
  constexpr int BLOADS = BN * 8 / 512;
  unsigned short* bbuf = buf + BM * 64;
#pragma unroll
  for (int i = 0; i < ALOADS; ++i) {
    const int s = i * 512 + tid, row = s >> 3, ch = s & 7;
    gl16(A + (size_t)(m0 + row) * K + kt + ((ch ^ (row & 7)) << 3), (char*)buf + s * 16);
  }
#pragma unroll
  for (int i = 0; i < BLOADS; ++i) {
    const int s = i * 512 + tid, row = s >> 3, ch = s & 7;
    gl16(BT + (size_t)(n0 + row) * K + kt + ((ch ^ (row & 7)) << 3), (char*)bbuf + s * 16);
  }
}

// MODE=0: qkv epilogue (cols<5120 -> bf16 qkvb stride QKV_LD; cols>=5120 -> vtg
//         transposed [col-5120][token]).  MODE=1: fp32 C = acc + resid.
template <int BM, int BN, int MODE, int GXLOG>
__global__ __launch_bounds__(512, 2) void k_gemm_big(const unsigned short* __restrict__ A,
                                                     const unsigned short* __restrict__ BT,
                                                     const float* __restrict__ resid,
                                                     void* __restrict__ Cout,
                                                     unsigned short* __restrict__ vtg,
                                                     int M, int N, int K) {
  extern __shared__ __align__(16) unsigned short lds[];
  constexpr int MREP = BM / 32;            // per-wave m fragments (2M wave rows)
  constexpr int NREP = BN / 64;            // per-wave n fragments (4N wave cols)
  constexpr int TILE = (BM + BN) * 64;     // elements per buffer
  constexpr int LOADS = (BM + BN) / 64;    // gl16 per thread per K-tile

  const int tid = threadIdx.x, lane = tid & 63;
  const int w = tid >> 6, wm = w >> 2, wn = w & 3;
  const int lr = lane & 15, lh = lane >> 4;

  // XCD-chunked bijective block swizzle (nwg % 8 == 0)
  const int nwg = gridDim.x * gridDim.y;
  const int wg0 = blockIdx.y * gridDim.x + blockIdx.x;
  const int swz = (wg0 & 7) * (nwg >> 3) + (wg0 >> 3);
  const int m0 = (swz >> GXLOG) * BM;
  const int n0 = (swz & ((1 << GXLOG) - 1)) * BN;

  const f32x4 zf = {0.f, 0.f, 0.f, 0.f};
  f32x4 acc[MREP][NREP];
#pragma unroll
  for (int i = 0; i < MREP; ++i) {
#pragma unroll
    for (int j = 0; j < NREP; ++j) acc[i][j] = zf;
  }

  const int arow0 = wm * (BM / 2);
  const int brow0 = wn * (BN / 4);
  const int NT = K >> 6;
  int cur = 0;

  stage_tile<BM, BN>(A, BT, lds, m0, n0, K, 0, tid);

  for (int t = 0; t < NT; ++t) {
    const unsigned short* abuf = lds + cur * TILE;
    const unsigned short* bbuf = abuf + BM * 64;
    if (t + 1 < NT) {
      stage_tile<BM, BN>(A, BT, lds + (cur ^ 1) * TILE, m0, n0, K, (t + 1) << 6, tid);
      waitvm<LOADS>();          // own stage(t) landed; stage(t+1) stays in flight
    } else {
      waitvm<0>();
    }
    __builtin_amdgcn_s_barrier();        // all waves' stage(t) visible
    __builtin_amdgcn_sched_barrier(0);

    short8 bfr[NREP][2];
#pragma unroll
    for (int nr = 0; nr < NREP; ++nr) {
#pragma unroll
      for (int kk = 0; kk < 2; ++kk)
        bfr[nr][kk] = rdfrag(bbuf, brow0 + nr * 16 + lr, kk * 4 + lh);
    }
#pragma unroll
    for (int mp = 0; mp < 4; ++mp) {
      short8 afr[2][2];
#pragma unroll
      for (int mi = 0; mi < 2; ++mi) {
#pragma unroll
        for (int kk = 0; kk < 2; ++kk)
          afr[mi][kk] = rdfrag(abuf, arow0 + (mp * 2 + mi) * 16 + lr, kk * 4 + lh);
      }
      __builtin_amdgcn_s_setprio(1);
#pragma unroll
      for (int mi = 0; mi < 2; ++mi) {
#pragma unroll
        for (int nr = 0; nr < NREP; ++nr) {
#pragma unroll
          for (int kk = 0; kk < 2; ++kk)
            acc[mp * 2 + mi][nr] = mfma16(afr[mi][kk], bfr[nr][kk], acc[mp * 2 + mi][nr]);
        }
      }
      __builtin_amdgcn_s_setprio(0);
    }
    __builtin_amdgcn_sched_barrier(0);
    __builtin_amdgcn_s_barrier();        // reads of buf[cur] done before overwrite
    cur ^= 1;
  }

  // ---- epilogue: C row = 4*lh + r, col = lr within each 16x16 tile
#pragma unroll
  for (int ai = 0; ai < MREP; ++ai) {
#pragma unroll
    for (int ni = 0; ni < NREP; ++ni) {
      const int colg = n0 + wn * (BN / 4) + ni * 16 + lr;
      const int rowg0 = m0 + wm * (BM / 2) + ai * 16 + 4 * lh;
      if (MODE == 1) {
#pragma unroll
        for (int r = 0; r < 4; ++r)
          ((float*)Cout)[(size_t)(rowg0 + r) * N + colg] =
              acc[ai][ni][r] + resid[(size_t)(rowg0 + r) * N + colg];
      } else if (colg >= 5120) {
        short4v o;
#pragma unroll
        for (int r = 0; r < 4; ++r) o[r] = (short)f2bf(acc[ai][ni][r]);
        *(short4v*)(vtg + (size_t)(colg - 5120) * TOK + rowg0) = o;
      } else {
#pragma unroll
        for (int r = 0; r < 4; ++r)
          ((unsigned short*)Cout)[(size_t)(rowg0 + r) * QKV_LD + colg] = f2bf(acc[ai][ni][r]);
      }
    }
  }
}

// ---------------- RoPE (in-place on q|k columns 0..5119) ----------------
__global__ __launch_bounds__(256) void k_rope(unsigned short* __restrict__ qkv,
                                              const float* __restrict__ rc,
                                              const float* __restrict__ rs) {
  const int row = blockIdx.y;
  const int p = blockIdx.x * 256 + threadIdx.x;  // pair 0..2559
  const int col = p * 2;
  const int d = col & 127;
  unsigned short* ptr = qkv + (size_t)row * QKV_LD + col;
  const unsigned both = *(const unsigned*)ptr;
  const float x0 = __uint_as_float((both & 0xffffu) << 16);
  const float x1 = __uint_as_float(both & 0xffff0000u);
  const float c0 = rc[row * 128 + d], c1 = rc[row * 128 + d + 1];
  const float s0 = rs[row * 128 + d], s1 = rs[row * 128 + d + 1];
  const float y0 = x0 * c0 - x1 * s0;
  const float y1 = x1 * c1 + x0 * s1;
  *(unsigned*)ptr = (unsigned)f2bf(y0) | ((unsigned)f2bf(y1) << 16);
}

// ---------------- Flash attention, causal, GQA ----------------
// grid (16 pairs, 32 heads); block = 4 waves x 16 q-rows = 64 q-rows.
// Each block does q-tile i then q-tile 31-i -> exactly 33 KV-tiles of 64.
__global__ __launch_bounds__(256) void k_attn(const unsigned short* __restrict__ qkv,
                                              const unsigned short* __restrict__ vtg,
                                              unsigned short* __restrict__ aout) {
  __shared__ __align__(16) unsigned short Ks[KVB * 128];      // 16KB, XOR-swizzled
  __shared__ __align__(16) unsigned short Vt[128 * KVB];      // 16KB, XOR-swizzled (V^T)
  __shared__ __align__(16) unsigned short Ps[4][16 * PS_LD];  // per-wave P, stride 72
  const int head = blockIdx.y;
  const int hkv = head >> 2;
  const int tid = threadIdx.x, lane = tid & 63, w = tid >> 6;
  const int lr = lane & 15, lh = lane >> 4;
  const float scale2 = 0.08838834764831845f * 1.44269504088896340736f;  // /sqrt(128)*log2(e)
  const f32x4 zf = {0.f, 0.f, 0.f, 0.f};

  for (int half = 0; half < 2; ++half) {
    const int qt = half ? (31 - blockIdx.x) : blockIdx.x;
    const int q0 = qt * 64;

    short8 qf[4];
    {
      const unsigned short* qbase = qkv + (size_t)(q0 + w * 16 + lr) * QKV_LD + head * 128;
#pragma unroll
      for (int kd = 0; kd < 4; ++kd) qf[kd] = *(const short8*)(qbase + kd * 32 + lh * 8);
    }
    f32x4 oacc[8];
#pragma unroll
    for (int vt = 0; vt < 8; ++vt) oacc[vt] = zf;
    float Mr[4], Lr[4];
#pragma unroll
    for (int r = 0; r < 4; ++r) { Mr[r] = -INFINITY; Lr[r] = 0.f; }

    const int nt = qt + 1;
    for (int t = 0; t < nt; ++t) {
      const int kv0 = t * KVB;
      __syncthreads();
      // stage K: 64 rows x 256B, pre-swizzled source chunks
#pragma unroll
      for (int c = 0; c < 4; ++c) {
        const int s = c * 256 + w * 64 + lane;
        const int row = s >> 4, cp = s & 15;
        gl16(qkv + (size_t)(kv0 + row) * QKV_LD + 4096 + hkv * 128 + ((cp ^ (row & 7)) * 8),
             (char*)Ks + (c * 256 + w * 64) * 16);
      }
      // stage V^T: 128 d-rows x 128B, pre-swizzled source chunks
#pragma unroll
      for (int c = 0; c < 4; ++c) {
        const int s = c * 256 + w * 64 + lane;
        const int row = s >> 3, cp = s & 7;
        gl16(vtg + (size_t)(hkv * 128 + row) * TOK + kv0 + ((cp ^ (row & 7)) * 8),
             (char*)Vt + (c * 256 + w * 64) * 16);
      }
      __syncthreads();

      // QK^T: S[16 q][64 kv] per wave
      f32x4 sacc[4];
#pragma unroll
      for (int ct = 0; ct < 4; ++ct) {
        sacc[ct] = zf;
        const int row = ct * 16 + lr;
#pragma unroll
        for (int kd = 0; kd < 4; ++kd) {
          const short8 kf = *(const short8*)((const char*)Ks + row * 256 +
                                             (((kd * 4 + lh) ^ (row & 7)) * 16));
          sacc[ct] = mfma16(qf[kd], kf, sacc[ct]);
        }
      }

      // online softmax (rows on 16-lane groups), exp2 domain
      float scv[4], pv[4][4];
#pragma unroll
      for (int r = 0; r < 4; ++r) {
        const int qrow = q0 + w * 16 + 4 * lh + r;
        float s0 = sacc[0][r] * scale2;
        float s1 = sacc[1][r] * scale2;
        float s2 = sacc[2][r] * scale2;
        float s3 = sacc[3][r] * scale2;
        if (kv0 + lr > qrow) s0 = -INFINITY;
        if (kv0 + 16 + lr > qrow) s1 = -INFINITY;
        if (kv0 + 32 + lr > qrow) s2 = -INFINITY;
        if (kv0 + 48 + lr > qrow) s3 = -INFINITY;
        float tmax = fmaxf(fmaxf(s0, s1), fmaxf(s2, s3));
        tmax = fmaxf(tmax, __shfl_xor(tmax, 1, 16));
        tmax = fmaxf(tmax, __shfl_xor(tmax, 2, 16));
        tmax = fmaxf(tmax, __shfl_xor(tmax, 4, 16));
        tmax = fmaxf(tmax, __shfl_xor(tmax, 8, 16));
        const float mnew = fmaxf(Mr[r], tmax);
        const float sc = fexp2(Mr[r] - mnew);
        Mr[r] = mnew;
        const float p0 = fexp2(s0 - mnew);
        const float p1 = fexp2(s1 - mnew);
        const float p2 = fexp2(s2 - mnew);
        const float p3 = fexp2(s3 - mnew);
        float ps = (p0 + p1) + (p2 + p3);
        ps += __shfl_xor(ps, 1, 16);
        ps += __shfl_xor(ps, 2, 16);
        ps += __shfl_xor(ps, 4, 16);
        ps += __shfl_xor(ps, 8, 16);
        Lr[r] = Lr[r] * sc + ps;
        scv[r] = sc;
        pv[r][0] = p0; pv[r][1] = p1; pv[r][2] = p2; pv[r][3] = p3;
      }
#pragma unroll
      for (int vt = 0; vt < 8; ++vt) {
#pragma unroll
        for (int r = 0; r < 4; ++r) oacc[vt][r] *= scv[r];
      }

      // P -> per-wave LDS (stride 72 >= 64 kv), then PV
      unsigned short* pw = Ps[w];
#pragma unroll
      for (int r = 0; r < 4; ++r) {
#pragma unroll
        for (int ct = 0; ct < 4; ++ct)
          pw[(4 * lh + r) * PS_LD + ct * 16 + lr] = f2bf(pv[r][ct]);
      }
      asm volatile("s_waitcnt lgkmcnt(0)" ::: "memory");
      short8 pf[2];
      pf[0] = *(const short8*)(pw + lr * PS_LD + lh * 8);
      pf[1] = *(const short8*)(pw + lr * PS_LD + 32 + lh * 8);
      __builtin_amdgcn_s_setprio(1);
#pragma unroll
      for (int vt = 0; vt < 8; ++vt) {
        const int d = vt * 16 + lr;
#pragma unroll
        for (int kb = 0; kb < 2; ++kb) {
          const short8 vf = *(const short8*)((const char*)Vt + d * 128 +
                                             (((kb * 4 + lh) ^ (lr & 7)) * 16));
          oacc[vt] = mfma16(pf[kb], vf, oacc[vt]);
        }
      }
      __builtin_amdgcn_s_setprio(0);
    }

    // epilogue for this q-tile
#pragma unroll
    for (int r = 0; r < 4; ++r) {
      const float inv = 1.0f / Lr[r];
      const size_t rowoff = (size_t)(q0 + w * 16 + 4 * lh + r) * DMODEL + head * 128;
#pragma unroll
      for (int vt = 0; vt < 8; ++vt)
        aout[rowoff + vt * 16 + lr] = f2bf(oacc[vt][r] * inv);
    }
  }
}

extern "C" void kernel_launch(void* const* d_in, const int* in_sizes, int n_in,
                              void* d_out, int out_size, void* d_ws, size_t ws_size,
                              hipStream_t stream) {
  (void)in_sizes; (void)n_in; (void)out_size; (void)ws_size;
  const float* x     = (const float*)d_in[0];
  const float* r_cos = (const float*)d_in[1];
  const float* r_sin = (const float*)d_in[2];
  const float* wnorm = (const float*)d_in[3];
  const float* wq    = (const float*)d_in[4];
  const float* wk    = (const float*)d_in[5];
  const float* wv    = (const float*)d_in[6];
  const float* wo    = (const float*)d_in[7];

  // ws layout (bf16 elems): bufA 8.39M | qkvb 10.49M | wT 25.17M | vtg 2.10M = 92.3MB
  unsigned short* bufA = (unsigned short*)d_ws;                  // h, later attn-out
  unsigned short* qkvb = bufA + (size_t)TOK * DMODEL;            // [2048][5120]
  unsigned short* wT   = qkvb + (size_t)TOK * QKV_LD;            // wqkv^T, later wo^T
  unsigned short* vtg  = wT + (size_t)6144 * DMODEL;             // V^T [1024][2048]

  // dynamic-LDS caps (idempotent, host-side; safe under graph capture)
  hipFuncSetAttribute((const void*)k_gemm_big<256, 192, 0, 5>,
                      hipFuncAttributeMaxDynamicSharedMemorySize, 4 * (256 + 192) * 64);
  hipFuncSetAttribute((const void*)k_gemm_big<256, 128, 1, 5>,
                      hipFuncAttributeMaxDynamicSharedMemorySize, 4 * (256 + 128) * 64);

  k_rmsnorm<<<TOK, 256, 0, stream>>>(x, wnorm, bufA);
  k_wconvert<<<dim3(64, 64), 256, 0, stream>>>(wq, wT, DMODEL, 4096);
  k_wconvert<<<dim3(16, 64), 256, 0, stream>>>(wk, wT + (size_t)4096 * DMODEL, DMODEL, 1024);
  k_wconvert<<<dim3(16, 64), 256, 0, stream>>>(wv, wT + (size_t)5120 * DMODEL, DMODEL, 1024);
  k_gemm_big<256, 192, 0, 5><<<dim3(256), 512, 4 * (256 + 192) * 64, stream>>>(
      bufA, wT, nullptr, qkvb, vtg, TOK, 6144, DMODEL);
  k_wconvert<<<dim3(64, 64), 256, 0, stream>>>(wo, wT, DMODEL, 4096);   // overlay: wo^T
  k_rope<<<dim3(10, TOK), 256, 0, stream>>>(qkvb, r_cos, r_sin);
  k_attn<<<dim3(16, 32), 256, 0, stream>>>(qkvb, vtg, bufA);
  k_gemm_big<256, 128, 1, 5><<<dim3(256), 512, 4 * (256 + 128) * 64, stream>>>(
      bufA, wT, x, d_out, nullptr, TOK, DMODEL, DMODEL);
}

// Round 6
// 334.715 us; speedup vs baseline: 1.0217x; 1.0217x over previous
//
#include <hip/hip_runtime.h>
#include <stdint.h>
#include <math.h>

#define TOK 2048
#define DMODEL 4096
#define QKV_LD 5120   // q(4096) | k(1024); V goes transposed to vtg
#define KVB 64
#define PS_LD 72      // 64 kv + 8 pad (P-tile LDS stride)

typedef __attribute__((ext_vector_type(8))) short short8;
typedef __attribute__((ext_vector_type(4))) short short4v;
typedef __attribute__((ext_vector_type(8))) __bf16 bf16x8;
typedef __attribute__((ext_vector_type(4))) float f32x4;

__device__ __forceinline__ unsigned short f2bf(float f) {
  unsigned u = __float_as_uint(f);
  u += 0x7fffu + ((u >> 16) & 1u);   // RNE
  return (unsigned short)(u >> 16);
}

__device__ __forceinline__ void gl16(const void* g, void* l) {
  __builtin_amdgcn_global_load_lds((__attribute__((address_space(1))) void*)g,
                                   (__attribute__((address_space(3))) void*)l,
                                   16, 0, 0);
}

__device__ __forceinline__ f32x4 mfma16(short8 a, short8 b, f32x4 c) {
  return __builtin_amdgcn_mfma_f32_16x16x32_bf16(__builtin_bit_cast(bf16x8, a),
                                                 __builtin_bit_cast(bf16x8, b),
                                                 c, 0, 0, 0);
}

__device__ __forceinline__ float fexp2(float x) {
  float r;
  asm("v_exp_f32 %0, %1" : "=v"(r) : "v"(x));
  return r;
}

// ---------------- RMSNorm: fp32 x -> bf16 h ----------------
__global__ __launch_bounds__(256) void k_rmsnorm(const float* __restrict__ x,
                                                 const float* __restrict__ w,
                                                 unsigned short* __restrict__ h) {
  const int row = blockIdx.x;
  const float* xr = x + (size_t)row * DMODEL;
  float4 v[4];
  float ss = 0.f;
#pragma unroll
  for (int i = 0; i < 4; ++i) {
    v[i] = *(const float4*)(xr + threadIdx.x * 4 + i * 1024);
    ss += v[i].x * v[i].x + v[i].y * v[i].y + v[i].z * v[i].z + v[i].w * v[i].w;
  }
#pragma unroll
  for (int m = 1; m < 64; m <<= 1) ss += __shfl_xor(ss, m, 64);
  __shared__ float ws4[4];
  if ((threadIdx.x & 63) == 0) ws4[threadIdx.x >> 6] = ss;
  __syncthreads();
  const float scale = rsqrtf((ws4[0] + ws4[1] + ws4[2] + ws4[3]) * (1.0f / DMODEL) + 1e-5f);
  unsigned short* hr = h + (size_t)row * DMODEL;
#pragma unroll
  for (int i = 0; i < 4; ++i) {
    int col = threadIdx.x * 4 + i * 1024;
    float4 wv = *(const float4*)(w + col);
    uint2 o;
    o.x = (unsigned)f2bf(v[i].x * scale * wv.x) | ((unsigned)f2bf(v[i].y * scale * wv.y) << 16);
    o.y = (unsigned)f2bf(v[i].z * scale * wv.z) | ((unsigned)f2bf(v[i].w * scale * wv.w) << 16);
    *(uint2*)(hr + col) = o;
  }
}

// ------- Weight convert+transpose: W[K][N] fp32 -> WT[N][K] bf16 -------
__global__ __launch_bounds__(256) void k_wconvert(const float* __restrict__ W,
                                                  unsigned short* __restrict__ WT,
                                                  int K, int N) {
  __shared__ unsigned short tile[64][65];
  const int n0 = blockIdx.x * 64, k0 = blockIdx.y * 64;
  const int t = threadIdx.x;
  {
    const int r = t >> 2, c0 = (t & 3) * 16;
    const float* src = W + (size_t)(k0 + r) * N + n0 + c0;
#pragma unroll
    for (int i = 0; i < 4; ++i) {
      float4 f = *(const float4*)(src + i * 4);
      tile[r][c0 + i * 4 + 0] = f2bf(f.x);
      tile[r][c0 + i * 4 + 1] = f2bf(f.y);
      tile[r][c0 + i * 4 + 2] = f2bf(f.z);
      tile[r][c0 + i * 4 + 3] = f2bf(f.w);
    }
  }
  __syncthreads();
  {
    const int n = t >> 2, c0 = (t & 3) * 16;
    unsigned short* dst = WT + (size_t)(n0 + n) * K + k0 + c0;
    unsigned short v[16];
#pragma unroll
    for (int i = 0; i < 16; ++i) v[i] = tile[c0 + i][n];
    uint4 o0, o1;
    o0.x = v[0] | ((unsigned)v[1] << 16);  o0.y = v[2] | ((unsigned)v[3] << 16);
    o0.z = v[4] | ((unsigned)v[5] << 16);  o0.w = v[6] | ((unsigned)v[7] << 16);
    o1.x = v[8] | ((unsigned)v[9] << 16);  o1.y = v[10] | ((unsigned)v[11] << 16);
    o1.z = v[12] | ((unsigned)v[13] << 16); o1.w = v[14] | ((unsigned)v[15] << 16);
    *(uint4*)dst = o0;
    *(uint4*)(dst + 8) = o1;
  }
}

// ======== Phase-interleaved GEMM: A[M][K] x BT[N][K] -> C[M][N] ========
// 8 waves (2M x 4N), BK=64, double-buffered LDS, XOR-swizzled tiles.
// 4 phases per K-tile: {ds_read A-pair || stage-half gl16} -> s_barrier ->
// setprio(1) MFMA cluster setprio(0) -> s_barrier. One __syncthreads per tile.
__device__ __forceinline__ short8 rdfrag(const unsigned short* buf, int row, int kc) {
  return *(const short8*)((const char*)buf + row * 128 + ((kc ^ (row & 7)) << 4));
}

template <int BM, int BN, int HALF>
__device__ __forceinline__ void stage_half(const unsigned short* __restrict__ A,
                                           const unsigned short* __restrict__ BT,
                                           unsigned short* __restrict__ buf,
                                           int m0, int n0, int K, int kt, int tid) {
  constexpr int AL = BM / 64, BL = BN / 64;
  constexpr int A0 = HALF ? AL / 2 : 0, A1 = HALF ? AL : AL / 2;
  constexpr int B0 = HALF ? BL / 2 : 0, B1 = HALF ? BL : BL / 2;
  unsigned short* bbuf = buf + BM * 64;
#pragma unroll
  for (int i = A0; i < A1; ++i) {
    const int s = i * 512 + tid, row = s >> 3, ch = s & 7;
    gl16(A + (size_t)(m0 + row) * K + kt + ((ch ^ (row & 7)) << 3), (char*)buf + s * 16);
  }
#pragma unroll
  for (int i = B0; i < B1; ++i) {
    const int s = i * 512 + tid, row = s >> 3, ch = s & 7;
    gl16(BT + (size_t)(n0 + row) * K + kt + ((ch ^ (row & 7)) << 3), (char*)bbuf + s * 16);
  }
}

// MODE=0: qkv epilogue (cols<5120 -> bf16 qkvb stride QKV_LD; cols>=5120 -> vtg
//         transposed [col-5120][token]).  MODE=1: fp32 C = acc + resid.
// Panel grid is (8 m) x (32 n) for both GEMMs; each XCD owns a 4m x 8n chunk.
template <int BM, int BN, int MODE>
__global__ __launch_bounds__(512, 2) void k_gemm_big(const unsigned short* __restrict__ A,
                                                     const unsigned short* __restrict__ BT,
                                                     const float* __restrict__ resid,
                                                     void* __restrict__ Cout,
                                                     unsigned short* __restrict__ vtg,
                                                     int M, int N, int K) {
  extern __shared__ __align__(16) unsigned short lds[];
  constexpr int MREP = BM / 32;            // per-wave m fragments (2M wave rows)
  constexpr int NREP = BN / 64;            // per-wave n fragments (4N wave cols)
  constexpr int TILE = (BM + BN) * 64;     // elements per buffer

  const int tid = threadIdx.x, lane = tid & 63;
  const int w = tid >> 6, wm = w >> 2, wn = w & 3;
  const int lr = lane & 15, lh = lane >> 4;

  // 2-D XCD chunking: XCD x = wg0&7 -> (x>>2, x&3) macro-cell; local l = wg0>>3
  // -> (l>>3, l&7) within cell. m-panel in [0,8), n-panel in [0,32). Bijective.
  const int wg0 = blockIdx.x;
  const int xcd = wg0 & 7, l = wg0 >> 3;
  const int m0 = (((xcd >> 2) << 2) + (l >> 3)) * BM;
  const int n0 = (((xcd & 3) << 3) + (l & 7)) * BN;

  const f32x4 zf = {0.f, 0.f, 0.f, 0.f};
  f32x4 acc[MREP][NREP];
#pragma unroll
  for (int i = 0; i < MREP; ++i) {
#pragma unroll
    for (int j = 0; j < NREP; ++j) acc[i][j] = zf;
  }

  const int arow0 = wm * (BM / 2);
  const int brow0 = wn * (BN / 4);
  const int NT = K >> 6;
  int cur = 0;

  stage_half<BM, BN, 0>(A, BT, lds, m0, n0, K, 0, tid);
  stage_half<BM, BN, 1>(A, BT, lds, m0, n0, K, 0, tid);
  __syncthreads();

  for (int t = 0; t < NT; ++t) {
    const unsigned short* abuf = lds + cur * TILE;
    const unsigned short* bbuf = abuf + BM * 64;
    unsigned short* nbuf = lds + (cur ^ 1) * TILE;
    const bool pre = (t + 1 < NT);
    const int ktn = (t + 1) << 6;

    short8 bfr[NREP][2];
#pragma unroll
    for (int nr = 0; nr < NREP; ++nr) {
#pragma unroll
      for (int kk = 0; kk < 2; ++kk)
        bfr[nr][kk] = rdfrag(bbuf, brow0 + nr * 16 + lr, kk * 4 + lh);
    }

#pragma unroll
    for (int p = 0; p < 4; ++p) {
      short8 afr[2][2];
#pragma unroll
      for (int mi = 0; mi < 2; ++mi) {
#pragma unroll
        for (int kk = 0; kk < 2; ++kk)
          afr[mi][kk] = rdfrag(abuf, arow0 + (p * 2 + mi) * 16 + lr, kk * 4 + lh);
      }
      if (p == 0 && pre) stage_half<BM, BN, 0>(A, BT, nbuf, m0, n0, K, ktn, tid);
      if (p == 1 && pre) stage_half<BM, BN, 1>(A, BT, nbuf, m0, n0, K, ktn, tid);
      __builtin_amdgcn_s_barrier();
      __builtin_amdgcn_s_setprio(1);
#pragma unroll
      for (int mi = 0; mi < 2; ++mi) {
#pragma unroll
        for (int nr = 0; nr < NREP; ++nr) {
#pragma unroll
          for (int kk = 0; kk < 2; ++kk)
            acc[p * 2 + mi][nr] = mfma16(afr[mi][kk], bfr[nr][kk], acc[p * 2 + mi][nr]);
        }
      }
      __builtin_amdgcn_s_setprio(0);
      if (p < 3) __builtin_amdgcn_s_barrier();
    }
    __syncthreads();   // drains stage(t+1) (issued >=2 phases ago) + read-done
    cur ^= 1;
  }

  // ---- epilogue: C row = 4*lh + r, col = lr within each 16x16 tile
#pragma unroll
  for (int ai = 0; ai < MREP; ++ai) {
#pragma unroll
    for (int ni = 0; ni < NREP; ++ni) {
      const int colg = n0 + wn * (BN / 4) + ni * 16 + lr;
      const int rowg0 = m0 + wm * (BM / 2) + ai * 16 + 4 * lh;
      if (MODE == 1) {
#pragma unroll
        for (int r = 0; r < 4; ++r)
          ((float*)Cout)[(size_t)(rowg0 + r) * N + colg] =
              acc[ai][ni][r] + resid[(size_t)(rowg0 + r) * N + colg];
      } else if (colg >= 5120) {
        short4v o;
#pragma unroll
        for (int r = 0; r < 4; ++r) o[r] = (short)f2bf(acc[ai][ni][r]);
        *(short4v*)(vtg + (size_t)(colg - 5120) * TOK + rowg0) = o;
      } else {
#pragma unroll
        for (int r = 0; r < 4; ++r)
          ((unsigned short*)Cout)[(size_t)(rowg0 + r) * QKV_LD + colg] = f2bf(acc[ai][ni][r]);
      }
    }
  }
}

// ---------------- RoPE (in-place on q|k columns 0..5119) ----------------
__global__ __launch_bounds__(256) void k_rope(unsigned short* __restrict__ qkv,
                                              const float* __restrict__ rc,
                                              const float* __restrict__ rs) {
  const int row = blockIdx.y;
  const int p = blockIdx.x * 256 + threadIdx.x;  // pair 0..2559
  const int col = p * 2;
  const int d = col & 127;
  unsigned short* ptr = qkv + (size_t)row * QKV_LD + col;
  const unsigned both = *(const unsigned*)ptr;
  const float x0 = __uint_as_float((both & 0xffffu) << 16);
  const float x1 = __uint_as_float(both & 0xffff0000u);
  const float c0 = rc[row * 128 + d], c1 = rc[row * 128 + d + 1];
  const float s0 = rs[row * 128 + d], s1 = rs[row * 128 + d + 1];
  const float y0 = x0 * c0 - x1 * s0;
  const float y1 = x1 * c1 + x0 * s1;
  *(unsigned*)ptr = (unsigned)f2bf(y0) | ((unsigned)f2bf(y1) << 16);
}

// ---------------- Flash attention, causal, GQA ----------------
// grid (16 pairs, 32 heads); block = 4 waves x 16 q-rows = 64 q-rows.
// Each block does q-tile i then q-tile 31-i -> exactly 33 KV-tiles of 64.
__global__ __launch_bounds__(256) void k_attn(const unsigned short* __restrict__ qkv,
                                              const unsigned short* __restrict__ vtg,
                                              unsigned short* __restrict__ aout) {
  __shared__ __align__(16) unsigned short Ks[KVB * 128];      // 16KB, XOR-swizzled
  __shared__ __align__(16) unsigned short Vt[128 * KVB];      // 16KB, XOR-swizzled (V^T)
  __shared__ __align__(16) unsigned short Ps[4][16 * PS_LD];  // per-wave P, stride 72
  const int head = blockIdx.y;
  const int hkv = head >> 2;
  const int tid = threadIdx.x, lane = tid & 63, w = tid >> 6;
  const int lr = lane & 15, lh = lane >> 4;
  const float scale2 = 0.08838834764831845f * 1.44269504088896340736f;  // /sqrt(128)*log2(e)
  const f32x4 zf = {0.f, 0.f, 0.f, 0.f};

  for (int half = 0; half < 2; ++half) {
    const int qt = half ? (31 - blockIdx.x) : blockIdx.x;
    const int q0 = qt * 64;

    short8 qf[4];
    {
      const unsigned short* qbase = qkv + (size_t)(q0 + w * 16 + lr) * QKV_LD + head * 128;
#pragma unroll
      for (int kd = 0; kd < 4; ++kd) qf[kd] = *(const short8*)(qbase + kd * 32 + lh * 8);
    }
    f32x4 oacc[8];
#pragma unroll
    for (int vt = 0; vt < 8; ++vt) oacc[vt] = zf;
    float Mr[4], Lr[4];
#pragma unroll
    for (int r = 0; r < 4; ++r) { Mr[r] = -INFINITY; Lr[r] = 0.f; }

    const int nt = qt + 1;
    for (int t = 0; t < nt; ++t) {
      const int kv0 = t * KVB;
      __syncthreads();
      // stage K: 64 rows x 256B, pre-swizzled source chunks
#pragma unroll
      for (int c = 0; c < 4; ++c) {
        const int s = c * 256 + w * 64 + lane;
        const int row = s >> 4, cp = s & 15;
        gl16(qkv + (size_t)(kv0 + row) * QKV_LD + 4096 + hkv * 128 + ((cp ^ (row & 7)) * 8),
             (char*)Ks + (c * 256 + w * 64) * 16);
      }
      // stage V^T: 128 d-rows x 128B, pre-swizzled source chunks
#pragma unroll
      for (int c = 0; c < 4; ++c) {
        const int s = c * 256 + w * 64 + lane;
        const int row = s >> 3, cp = s & 7;
        gl16(vtg + (size_t)(hkv * 128 + row) * TOK + kv0 + ((cp ^ (row & 7)) * 8),
             (char*)Vt + (c * 256 + w * 64) * 16);
      }
      __syncthreads();

      // QK^T: S[16 q][64 kv] per wave
      f32x4 sacc[4];
#pragma unroll
      for (int ct = 0; ct < 4; ++ct) {
        sacc[ct] = zf;
        const int row = ct * 16 + lr;
#pragma unroll
        for (int kd = 0; kd < 4; ++kd) {
          const short8 kf = *(const short8*)((const char*)Ks + row * 256 +
                                             (((kd * 4 + lh) ^ (row & 7)) * 16));
          sacc[ct] = mfma16(qf[kd], kf, sacc[ct]);
        }
      }

      // online softmax (rows on 16-lane groups), exp2 domain
      float scv[4], pv[4][4];
#pragma unroll
      for (int r = 0; r < 4; ++r) {
        const int qrow = q0 + w * 16 + 4 * lh + r;
        float s0 = sacc[0][r] * scale2;
        float s1 = sacc[1][r] * scale2;
        float s2 = sacc[2][r] * scale2;
        float s3 = sacc[3][r] * scale2;
        if (kv0 + lr > qrow) s0 = -INFINITY;
        if (kv0 + 16 + lr > qrow) s1 = -INFINITY;
        if (kv0 + 32 + lr > qrow) s2 = -INFINITY;
        if (kv0 + 48 + lr > qrow) s3 = -INFINITY;
        float tmax = fmaxf(fmaxf(s0, s1), fmaxf(s2, s3));
        tmax = fmaxf(tmax, __shfl_xor(tmax, 1, 16));
        tmax = fmaxf(tmax, __shfl_xor(tmax, 2, 16));
        tmax = fmaxf(tmax, __shfl_xor(tmax, 4, 16));
        tmax = fmaxf(tmax, __shfl_xor(tmax, 8, 16));
        const float mnew = fmaxf(Mr[r], tmax);
        const float sc = fexp2(Mr[r] - mnew);
        Mr[r] = mnew;
        const float p0 = fexp2(s0 - mnew);
        const float p1 = fexp2(s1 - mnew);
        const float p2 = fexp2(s2 - mnew);
        const float p3 = fexp2(s3 - mnew);
        float ps = (p0 + p1) + (p2 + p3);
        ps += __shfl_xor(ps, 1, 16);
        ps += __shfl_xor(ps, 2, 16);
        ps += __shfl_xor(ps, 4, 16);
        ps += __shfl_xor(ps, 8, 16);
        Lr[r] = Lr[r] * sc + ps;
        scv[r] = sc;
        pv[r][0] = p0; pv[r][1] = p1; pv[r][2] = p2; pv[r][3] = p3;
      }
#pragma unroll
      for (int vt = 0; vt < 8; ++vt) {
#pragma unroll
        for (int r = 0; r < 4; ++r) oacc[vt][r] *= scv[r];
      }

      // P -> per-wave LDS (stride 72 >= 64 kv), then PV
      unsigned short* pw = Ps[w];
#pragma unroll
      for (int r = 0; r < 4; ++r) {
#pragma unroll
        for (int ct = 0; ct < 4; ++ct)
          pw[(4 * lh + r) * PS_LD + ct * 16 + lr] = f2bf(pv[r][ct]);
      }
      asm volatile("s_waitcnt lgkmcnt(0)" ::: "memory");
      short8 pf[2];
      pf[0] = *(const short8*)(pw + lr * PS_LD + lh * 8);
      pf[1] = *(const short8*)(pw + lr * PS_LD + 32 + lh * 8);
      __builtin_amdgcn_s_setprio(1);
#pragma unroll
      for (int vt = 0; vt < 8; ++vt) {
        const int d = vt * 16 + lr;
#pragma unroll
        for (int kb = 0; kb < 2; ++kb) {
          const short8 vf = *(const short8*)((const char*)Vt + d * 128 +
                                             (((kb * 4 + lh) ^ (lr & 7)) * 16));
          oacc[vt] = mfma16(pf[kb], vf, oacc[vt]);
        }
      }
      __builtin_amdgcn_s_setprio(0);
    }

    // epilogue for this q-tile
#pragma unroll
    for (int r = 0; r < 4; ++r) {
      const float inv = 1.0f / Lr[r];
      const size_t rowoff = (size_t)(q0 + w * 16 + 4 * lh + r) * DMODEL + head * 128;
#pragma unroll
      for (int vt = 0; vt < 8; ++vt)
        aout[rowoff + vt * 16 + lr] = f2bf(oacc[vt][r] * inv);
    }
  }
}

extern "C" void kernel_launch(void* const* d_in, const int* in_sizes, int n_in,
                              void* d_out, int out_size, void* d_ws, size_t ws_size,
                              hipStream_t stream) {
  (void)in_sizes; (void)n_in; (void)out_size; (void)ws_size;
  const float* x     = (const float*)d_in[0];
  const float* r_cos = (const float*)d_in[1];
  const float* r_sin = (const float*)d_in[2];
  const float* wnorm = (const float*)d_in[3];
  const float* wq    = (const float*)d_in[4];
  const float* wk    = (const float*)d_in[5];
  const float* wv    = (const float*)d_in[6];
  const float* wo    = (const float*)d_in[7];

  // ws layout (bf16 elems): bufA 8.39M | qkvb 10.49M | wT 25.17M | vtg 2.10M = 92.3MB
  unsigned short* bufA = (unsigned short*)d_ws;                  // h, later attn-out
  unsigned short* qkvb = bufA + (size_t)TOK * DMODEL;            // [2048][5120]
  unsigned short* wT   = qkvb + (size_t)TOK * QKV_LD;            // wqkv^T, later wo^T
  unsigned short* vtg  = wT + (size_t)6144 * DMODEL;             // V^T [1024][2048]

  // dynamic-LDS caps (idempotent, host-side; safe under graph capture)
  hipFuncSetAttribute((const void*)k_gemm_big<256, 192, 0>,
                      hipFuncAttributeMaxDynamicSharedMemorySize, 4 * (256 + 192) * 64);
  hipFuncSetAttribute((const void*)k_gemm_big<256, 128, 1>,
                      hipFuncAttributeMaxDynamicSharedMemorySize, 4 * (256 + 128) * 64);

  k_rmsnorm<<<TOK, 256, 0, stream>>>(x, wnorm, bufA);
  k_wconvert<<<dim3(64, 64), 256, 0, stream>>>(wq, wT, DMODEL, 4096);
  k_wconvert<<<dim3(16, 64), 256, 0, stream>>>(wk, wT + (size_t)4096 * DMODEL, DMODEL, 1024);
  k_wconvert<<<dim3(16, 64), 256, 0, stream>>>(wv, wT + (size_t)5120 * DMODEL, DMODEL, 1024);
  k_gemm_big<256, 192, 0><<<dim3(256), 512, 4 * (256 + 192) * 64, stream>>>(
      bufA, wT, nullptr, qkvb, vtg, TOK, 6144, DMODEL);
  k_wconvert<<<dim3(64, 64), 256, 0, stream>>>(wo, wT, DMODEL, 4096);   // overlay: wo^T
  k_rope<<<dim3(10, TOK), 256, 0, stream>>>(qkvb, r_cos, r_sin);
  k_attn<<<dim3(16, 32), 256, 0, stream>>>(qkvb, vtg, bufA);
  k_gemm_big<256, 128, 1><<<dim3(256), 512, 4 * (256 + 128) * 64, stream>>>(
      bufA, wT, x, d_out, nullptr, TOK, DMODEL, DMODEL);
}

// Round 7
// 325.805 us; speedup vs baseline: 1.0496x; 1.0273x over previous
//
#include <hip/hip_runtime.h>
#include <stdint.h>
#include <math.h>

#define TOK 2048
#define DMODEL 4096
#define QKV_LD 5120   // q(4096) | k(1024); V goes transposed to vtg
#define KVB 64
#define PS_LD 72      // 64 kv + 8 pad (P-tile LDS stride)

typedef __attribute__((ext_vector_type(8))) short short8;
typedef __attribute__((ext_vector_type(4))) short short4v;
typedef __attribute__((ext_vector_type(8))) __bf16 bf16x8;
typedef __attribute__((ext_vector_type(4))) float f32x4;

__device__ __forceinline__ unsigned short f2bf(float f) {
  unsigned u = __float_as_uint(f);
  u += 0x7fffu + ((u >> 16) & 1u);   // RNE
  return (unsigned short)(u >> 16);
}

__device__ __forceinline__ void gl16(const void* g, void* l) {
  __builtin_amdgcn_global_load_lds((__attribute__((address_space(1))) void*)g,
                                   (__attribute__((address_space(3))) void*)l,
                                   16, 0, 0);
}

__device__ __forceinline__ f32x4 mfma16(short8 a, short8 b, f32x4 c) {
  return __builtin_amdgcn_mfma_f32_16x16x32_bf16(__builtin_bit_cast(bf16x8, a),
                                                 __builtin_bit_cast(bf16x8, b),
                                                 c, 0, 0, 0);
}

__device__ __forceinline__ float fexp2(float x) {
  float r;
  asm("v_exp_f32 %0, %1" : "=v"(r) : "v"(x));
  return r;
}

template <int N>
__device__ __forceinline__ void waitvm() {
  if constexpr (N == 0) asm volatile("s_waitcnt vmcnt(0)" ::: "memory");
  else if constexpr (N == 3) asm volatile("s_waitcnt vmcnt(3)" ::: "memory");
  else if constexpr (N == 4) asm volatile("s_waitcnt vmcnt(4)" ::: "memory");
  else if constexpr (N == 8) asm volatile("s_waitcnt vmcnt(8)" ::: "memory");
  else static_assert(N == 0 || N == 3 || N == 4 || N == 8, "add literal");
}

// ---------------- RMSNorm: fp32 x -> bf16 h ----------------
__global__ __launch_bounds__(256) void k_rmsnorm(const float* __restrict__ x,
                                                 const float* __restrict__ w,
                                                 unsigned short* __restrict__ h) {
  const int row = blockIdx.x;
  const float* xr = x + (size_t)row * DMODEL;
  float4 v[4];
  float ss = 0.f;
#pragma unroll
  for (int i = 0; i < 4; ++i) {
    v[i] = *(const float4*)(xr + threadIdx.x * 4 + i * 1024);
    ss += v[i].x * v[i].x + v[i].y * v[i].y + v[i].z * v[i].z + v[i].w * v[i].w;
  }
#pragma unroll
  for (int m = 1; m < 64; m <<= 1) ss += __shfl_xor(ss, m, 64);
  __shared__ float ws4[4];
  if ((threadIdx.x & 63) == 0) ws4[threadIdx.x >> 6] = ss;
  __syncthreads();
  const float scale = rsqrtf((ws4[0] + ws4[1] + ws4[2] + ws4[3]) * (1.0f / DMODEL) + 1e-5f);
  unsigned short* hr = h + (size_t)row * DMODEL;
#pragma unroll
  for (int i = 0; i < 4; ++i) {
    int col = threadIdx.x * 4 + i * 1024;
    float4 wv = *(const float4*)(w + col);
    uint2 o;
    o.x = (unsigned)f2bf(v[i].x * scale * wv.x) | ((unsigned)f2bf(v[i].y * scale * wv.y) << 16);
    o.y = (unsigned)f2bf(v[i].z * scale * wv.z) | ((unsigned)f2bf(v[i].w * scale * wv.w) << 16);
    *(uint2*)(hr + col) = o;
  }
}

// ------- Weight convert+transpose: W[K][N] fp32 -> WT[N][K] bf16 -------
__global__ __launch_bounds__(256) void k_wconvert(const float* __restrict__ W,
                                                  unsigned short* __restrict__ WT,
                                                  int K, int N) {
  __shared__ unsigned short tile[64][65];
  const int n0 = blockIdx.x * 64, k0 = blockIdx.y * 64;
  const int t = threadIdx.x;
  {
    const int r = t >> 2, c0 = (t & 3) * 16;
    const float* src = W + (size_t)(k0 + r) * N + n0 + c0;
#pragma unroll
    for (int i = 0; i < 4; ++i) {
      float4 f = *(const float4*)(src + i * 4);
      tile[r][c0 + i * 4 + 0] = f2bf(f.x);
      tile[r][c0 + i * 4 + 1] = f2bf(f.y);
      tile[r][c0 + i * 4 + 2] = f2bf(f.z);
      tile[r][c0 + i * 4 + 3] = f2bf(f.w);
    }
  }
  __syncthreads();
  {
    const int n = t >> 2, c0 = (t & 3) * 16;
    unsigned short* dst = WT + (size_t)(n0 + n) * K + k0 + c0;
    unsigned short v[16];
#pragma unroll
    for (int i = 0; i < 16; ++i) v[i] = tile[c0 + i][n];
    uint4 o0, o1;
    o0.x = v[0] | ((unsigned)v[1] << 16);  o0.y = v[2] | ((unsigned)v[3] << 16);
    o0.z = v[4] | ((unsigned)v[5] << 16);  o0.w = v[6] | ((unsigned)v[7] << 16);
    o1.x = v[8] | ((unsigned)v[9] << 16);  o1.y = v[10] | ((unsigned)v[11] << 16);
    o1.z = v[12] | ((unsigned)v[13] << 16); o1.w = v[14] | ((unsigned)v[15] << 16);
    *(uint4*)dst = o0;
    *(uint4*)(dst + 8) = o1;
  }
}

// ======== Counted 2-barrier GEMM: A[M][K] x BT[N][K] -> C[M][N] ========
// 8 waves (2M x 4N), BK=64, double-buffered LDS, XOR-swizzled tiles.
// Per K-tile: P0 {stage h0 -> vmcnt(H0) -> barrier -> reads -> MFMA},
// P1 {stage h1 || reads/MFMA}, P2 {reads/MFMA}, P3 {reads -> lgkmcnt(0)
// -> barrier -> MFMA}. Loads never drained mid-loop.
__device__ __forceinline__ short8 rdfrag(const unsigned short* buf, int row, int kc) {
  return *(const short8*)((const char*)buf + row * 128 + ((kc ^ (row & 7)) << 4));
}

template <int BM, int BN, int HALF>
__device__ __forceinline__ void stage_half(const unsigned short* __restrict__ A,
                                           const unsigned short* __restrict__ BT,
                                           unsigned short* __restrict__ buf,
                                           int m0, int n0, int K, int kt, int tid) {
  constexpr int LA = BM / 64, LB = BN / 64;
  constexpr int H0A = LA / 2, H0B = (LB + 1) / 2;
  constexpr int A0 = HALF ? H0A : 0, A1 = HALF ? LA : H0A;
  constexpr int B0 = HALF ? H0B : 0, B1 = HALF ? LB : H0B;
  unsigned short* bbuf = buf + BM * 64;
#pragma unroll
  for (int i = A0; i < A1; ++i) {
    const int s = i * 512 + tid, row = s >> 3, ch = s & 7;
    gl16(A + (size_t)(m0 + row) * K + kt + ((ch ^ (row & 7)) << 3), (char*)buf + s * 16);
  }
#pragma unroll
  for (int i = B0; i < B1; ++i) {
    const int s = i * 512 + tid, row = s >> 3, ch = s & 7;
    gl16(BT + (size_t)(n0 + row) * K + kt + ((ch ^ (row & 7)) << 3), (char*)bbuf + s * 16);
  }
}

// MODE=0: qkv epilogue with fused RoPE (cols<5120 -> roped bf16 qkvb;
//         cols>=5120 -> vtg transposed).  MODE=1: fp32 C = acc + resid.
// Panel grid is (8 m) x (32 n) for both GEMMs; each XCD owns a 4m x 8n chunk.
template <int BM, int BN, int MODE>
__global__ __launch_bounds__(512, 2) void k_gemm_big(const unsigned short* __restrict__ A,
                                                     const unsigned short* __restrict__ BT,
                                                     const float* __restrict__ resid,
                                                     void* __restrict__ Cout,
                                                     unsigned short* __restrict__ vtg,
                                                     const float* __restrict__ rc,
                                                     const float* __restrict__ rs,
                                                     int M, int N, int K) {
  extern __shared__ __align__(16) unsigned short lds[];
  constexpr int MREP = BM / 32;            // 8 (two halves of 4)
  constexpr int NREP = BN / 64;            // 3 (qkv) / 2 (out)
  constexpr int TILE = (BM + BN) * 64;
  constexpr int LA = BM / 64, LB = BN / 64;
  constexpr int H0 = LA / 2 + (LB + 1) / 2;   // loads issued in P0

  const int tid = threadIdx.x, lane = tid & 63;
  const int w = tid >> 6, wm = w >> 2, wn = w & 3;
  const int lr = lane & 15, lh = lane >> 4;

  // 2-D XCD chunking over the 8x32 panel grid (bijective)
  const int wg0 = blockIdx.x;
  const int xcd = wg0 & 7, l = wg0 >> 3;
  const int m0 = (((xcd >> 2) << 2) + (l >> 3)) * BM;
  const int n0 = (((xcd & 3) << 3) + (l & 7)) * BN;

  const f32x4 zf = {0.f, 0.f, 0.f, 0.f};
  f32x4 acc[MREP][NREP];
#pragma unroll
  for (int i = 0; i < MREP; ++i) {
#pragma unroll
    for (int j = 0; j < NREP; ++j) acc[i][j] = zf;
  }

  const int arow0 = wm * (BM / 2);
  const int brow0 = wn * (BN / 4);
  const int NT = K >> 6;
  int cur = 0;

  stage_half<BM, BN, 0>(A, BT, lds, m0, n0, K, 0, tid);
  stage_half<BM, BN, 1>(A, BT, lds, m0, n0, K, 0, tid);

  for (int t = 0; t < NT; ++t) {
    const unsigned short* abuf = lds + cur * TILE;
    const unsigned short* bbuf = abuf + BM * 64;
    unsigned short* nbuf = lds + (cur ^ 1) * TILE;
    const bool pre = (t + 1 < NT);
    const int ktn = (t + 1) << 6;

    short8 bfr[NREP], afr[4];
    // ---- P0: stage h0(t+1), counted wait for tile t, barrier, kk0 h0
    if (pre) {
      stage_half<BM, BN, 0>(A, BT, nbuf, m0, n0, K, ktn, tid);
      waitvm<H0>();
    } else {
      waitvm<0>();
    }
    __builtin_amdgcn_s_barrier();
#pragma unroll
    for (int nr = 0; nr < NREP; ++nr) bfr[nr] = rdfrag(bbuf, brow0 + nr * 16 + lr, lh);
#pragma unroll
    for (int mi = 0; mi < 4; ++mi) afr[mi] = rdfrag(abuf, arow0 + mi * 16 + lr, lh);
    __builtin_amdgcn_s_setprio(1);
#pragma unroll
    for (int mi = 0; mi < 4; ++mi) {
#pragma unroll
      for (int nr = 0; nr < NREP; ++nr)
        acc[mi][nr] = mfma16(afr[mi], bfr[nr], acc[mi][nr]);
    }
    __builtin_amdgcn_s_setprio(0);
    // ---- P1: stage h1(t+1) || kk0 h1
    if (pre) stage_half<BM, BN, 1>(A, BT, nbuf, m0, n0, K, ktn, tid);
#pragma unroll
    for (int mi = 0; mi < 4; ++mi) afr[mi] = rdfrag(abuf, arow0 + (4 + mi) * 16 + lr, lh);
    __builtin_amdgcn_s_setprio(1);
#pragma unroll
    for (int mi = 0; mi < 4; ++mi) {
#pragma unroll
      for (int nr = 0; nr < NREP; ++nr)
        acc[4 + mi][nr] = mfma16(afr[mi], bfr[nr], acc[4 + mi][nr]);
    }
    __builtin_amdgcn_s_setprio(0);
    // ---- P2: kk1 h0
#pragma unroll
    for (int nr = 0; nr < NREP; ++nr) bfr[nr] = rdfrag(bbuf, brow0 + nr * 16 + lr, 4 + lh);
#pragma unroll
    for (int mi = 0; mi < 4; ++mi) afr[mi] = rdfrag(abuf, arow0 + mi * 16 + lr, 4 + lh);
    __builtin_amdgcn_s_setprio(1);
#pragma unroll
    for (int mi = 0; mi < 4; ++mi) {
#pragma unroll
      for (int nr = 0; nr < NREP; ++nr)
        acc[mi][nr] = mfma16(afr[mi], bfr[nr], acc[mi][nr]);
    }
    __builtin_amdgcn_s_setprio(0);
    // ---- P3: kk1 h1; all reads done -> barrier (frees buf[cur]) -> MFMA
#pragma unroll
    for (int mi = 0; mi < 4; ++mi) afr[mi] = rdfrag(abuf, arow0 + (4 + mi) * 16 + lr, 4 + lh);
    asm volatile("s_waitcnt lgkmcnt(0)" ::: "memory");
    __builtin_amdgcn_s_barrier();
    __builtin_amdgcn_s_setprio(1);
#pragma unroll
    for (int mi = 0; mi < 4; ++mi) {
#pragma unroll
      for (int nr = 0; nr < NREP; ++nr)
        acc[4 + mi][nr] = mfma16(afr[mi], bfr[nr], acc[4 + mi][nr]);
    }
    __builtin_amdgcn_s_setprio(0);
    cur ^= 1;
  }

  // ---- epilogue: C row = 4*lh + r, col = lr within each 16x16 tile
#pragma unroll
  for (int ai = 0; ai < MREP; ++ai) {
#pragma unroll
    for (int ni = 0; ni < NREP; ++ni) {
      const int colg = n0 + wn * (BN / 4) + ni * 16 + lr;
      const int rowg0 = m0 + wm * (BM / 2) + ai * 16 + 4 * lh;
      if (MODE == 1) {
#pragma unroll
        for (int r = 0; r < 4; ++r)
          ((float*)Cout)[(size_t)(rowg0 + r) * N + colg] =
              acc[ai][ni][r] + resid[(size_t)(rowg0 + r) * N + colg];
      } else if (colg >= 5120) {
        short4v o;
#pragma unroll
        for (int r = 0; r < 4; ++r) o[r] = (short)f2bf(acc[ai][ni][r]);
        *(short4v*)(vtg + (size_t)(colg - 5120) * TOK + rowg0) = o;
      } else {
        // fused RoPE: pair (even,odd) cols live in adjacent lanes
        const int d = colg & 127;
#pragma unroll
        for (int r = 0; r < 4; ++r) {
          const int row = rowg0 + r;
          const float v = acc[ai][ni][r];
          const float p = __shfl_xor(v, 1, 64);
          const float c = rc[row * 128 + d];
          const float s = rs[row * 128 + d];
          const float y = (lr & 1) ? fmaf(p, s, v * c) : fmaf(-p, s, v * c);
          ((unsigned short*)Cout)[(size_t)row * QKV_LD + colg] = f2bf(y);
        }
      }
    }
  }
}

// ---------------- Flash attention, causal, GQA ----------------
// grid (16 pairs, 32 heads); block = 4 waves x 16 q-rows = 64 q-rows.
// Double-buffered K/V staging with counted vmcnt(8); 2 barriers per KV-tile.
__global__ __launch_bounds__(256) void k_attn(const unsigned short* __restrict__ qkv,
                                              const unsigned short* __restrict__ vtg,
                                              unsigned short* __restrict__ aout) {
  extern __shared__ __align__(16) unsigned short sm[];
  unsigned short* const KsB = sm;                    // [2][KVB*128]
  unsigned short* const VtB = sm + 2 * KVB * 128;    // [2][128*KVB]
  unsigned short* const Ps = sm + 4 * KVB * 128;     // [4][16*PS_LD]
  const int head = blockIdx.y;
  const int hkv = head >> 2;
  const int tid = threadIdx.x, lane = tid & 63, w = tid >> 6;
  const int lr = lane & 15, lh = lane >> 4;
  const float scale2 = 0.08838834764831845f * 1.44269504088896340736f;  // /sqrt(128)*log2(e)
  const f32x4 zf = {0.f, 0.f, 0.f, 0.f};

  for (int half = 0; half < 2; ++half) {
    const int qt = half ? (31 - blockIdx.x) : blockIdx.x;
    const int q0 = qt * 64;

    short8 qf[4];
    {
      const unsigned short* qbase = qkv + (size_t)(q0 + w * 16 + lr) * QKV_LD + head * 128;
#pragma unroll
      for (int kd = 0; kd < 4; ++kd) qf[kd] = *(const short8*)(qbase + kd * 32 + lh * 8);
    }
    f32x4 oacc[8];
#pragma unroll
    for (int vt = 0; vt < 8; ++vt) oacc[vt] = zf;
    float Mr[4], Lr[4];
#pragma unroll
    for (int r = 0; r < 4; ++r) { Mr[r] = -INFINITY; Lr[r] = 0.f; }

    const int nt = qt + 1;
    int cur = 0;

    // prologue: stage tile 0 into buffer 0 (8 gl16 per thread)
    {
#pragma unroll
      for (int c = 0; c < 4; ++c) {
        const int s = c * 256 + w * 64 + lane;
        const int row = s >> 4, cp = s & 15;
        gl16(qkv + (size_t)row * QKV_LD + 4096 + hkv * 128 + ((cp ^ (row & 7)) * 8),
             (char*)KsB + (c * 256 + w * 64) * 16);
      }
#pragma unroll
      for (int c = 0; c < 4; ++c) {
        const int s = c * 256 + w * 64 + lane;
        const int row = s >> 3, cp = s & 7;
        gl16(vtg + (size_t)(hkv * 128 + row) * TOK + ((cp ^ (row & 7)) * 8),
             (char*)VtB + (c * 256 + w * 64) * 16);
      }
    }

    for (int t = 0; t < nt; ++t) {
      const unsigned short* Ks = KsB + cur * (KVB * 128);
      const unsigned short* Vt = VtB + cur * (128 * KVB);
      const int kv0 = t * KVB;
      // prefetch tile t+1 into the other buffer, counted wait for tile t
      if (t + 1 < nt) {
        unsigned short* Ksn = KsB + (cur ^ 1) * (KVB * 128);
        unsigned short* Vtn = VtB + (cur ^ 1) * (128 * KVB);
        const int kvn = (t + 1) * KVB;
#pragma unroll
        for (int c = 0; c < 4; ++c) {
          const int s = c * 256 + w * 64 + lane;
          const int row = s >> 4, cp = s & 15;
          gl16(qkv + (size_t)(kvn + row) * QKV_LD + 4096 + hkv * 128 + ((cp ^ (row & 7)) * 8),
               (char*)Ksn + (c * 256 + w * 64) * 16);
        }
#pragma unroll
        for (int c = 0; c < 4; ++c) {
          const int s = c * 256 + w * 64 + lane;
          const int row = s >> 3, cp = s & 7;
          gl16(vtg + (size_t)(hkv * 128 + row) * TOK + kvn + ((cp ^ (row & 7)) * 8),
               (char*)Vtn + (c * 256 + w * 64) * 16);
        }
        waitvm<8>();
      } else {
        waitvm<0>();
      }
      __builtin_amdgcn_s_barrier();

      // QK^T: S[16 q][64 kv] per wave
      f32x4 sacc[4];
#pragma unroll
      for (int ct = 0; ct < 4; ++ct) {
        sacc[ct] = zf;
        const int row = ct * 16 + lr;
#pragma unroll
        for (int kd = 0; kd < 4; ++kd) {
          const short8 kf = *(const short8*)((const char*)Ks + row * 256 +
                                             (((kd * 4 + lh) ^ (row & 7)) * 16));
          sacc[ct] = mfma16(qf[kd], kf, sacc[ct]);
        }
      }

      // online softmax (rows on 16-lane groups), exp2 domain
      float scv[4], pv[4][4];
#pragma unroll
      for (int r = 0; r < 4; ++r) {
        const int qrow = q0 + w * 16 + 4 * lh + r;
        float s0 = sacc[0][r] * scale2;
        float s1 = sacc[1][r] * scale2;
        float s2 = sacc[2][r] * scale2;
        float s3 = sacc[3][r] * scale2;
        if (kv0 + lr > qrow) s0 = -INFINITY;
        if (kv0 + 16 + lr > qrow) s1 = -INFINITY;
        if (kv0 + 32 + lr > qrow) s2 = -INFINITY;
        if (kv0 + 48 + lr > qrow) s3 = -INFINITY;
        float tmax = fmaxf(fmaxf(s0, s1), fmaxf(s2, s3));
        tmax = fmaxf(tmax, __shfl_xor(tmax, 1, 16));
        tmax = fmaxf(tmax, __shfl_xor(tmax, 2, 16));
        tmax = fmaxf(tmax, __shfl_xor(tmax, 4, 16));
        tmax = fmaxf(tmax, __shfl_xor(tmax, 8, 16));
        const float mnew = fmaxf(Mr[r], tmax);
        const float sc = fexp2(Mr[r] - mnew);
        Mr[r] = mnew;
        const float p0 = fexp2(s0 - mnew);
        const float p1 = fexp2(s1 - mnew);
        const float p2 = fexp2(s2 - mnew);
        const float p3 = fexp2(s3 - mnew);
        float ps = (p0 + p1) + (p2 + p3);
        ps += __shfl_xor(ps, 1, 16);
        ps += __shfl_xor(ps, 2, 16);
        ps += __shfl_xor(ps, 4, 16);
        ps += __shfl_xor(ps, 8, 16);
        Lr[r] = Lr[r] * sc + ps;
        scv[r] = sc;
        pv[r][0] = p0; pv[r][1] = p1; pv[r][2] = p2; pv[r][3] = p3;
      }
#pragma unroll
      for (int vt = 0; vt < 8; ++vt) {
#pragma unroll
        for (int r = 0; r < 4; ++r) oacc[vt][r] *= scv[r];
      }

      // P -> per-wave LDS (stride 72 >= 64 kv), then PV
      unsigned short* pw = Ps + w * (16 * PS_LD);
#pragma unroll
      for (int r = 0; r < 4; ++r) {
#pragma unroll
        for (int ct = 0; ct < 4; ++ct)
          pw[(4 * lh + r) * PS_LD + ct * 16 + lr] = f2bf(pv[r][ct]);
      }
      asm volatile("s_waitcnt lgkmcnt(0)" ::: "memory");
      short8 pf[2];
      pf[0] = *(const short8*)(pw + lr * PS_LD + lh * 8);
      pf[1] = *(const short8*)(pw + lr * PS_LD + 32 + lh * 8);
      __builtin_amdgcn_s_setprio(1);
#pragma unroll
      for (int vt = 0; vt < 8; ++vt) {
        const int d = vt * 16 + lr;
#pragma unroll
        for (int kb = 0; kb < 2; ++kb) {
          const short8 vf = *(const short8*)((const char*)Vt + d * 128 +
                                             (((kb * 4 + lh) ^ (lr & 7)) * 16));
          oacc[vt] = mfma16(pf[kb], vf, oacc[vt]);
        }
      }
      __builtin_amdgcn_s_setprio(0);
      // all reads of buf[cur] done -> safe for next tile's stage overwrite
      asm volatile("s_waitcnt lgkmcnt(0)" ::: "memory");
      __builtin_amdgcn_s_barrier();
      cur ^= 1;
    }

    // epilogue for this q-tile
#pragma unroll
    for (int r = 0; r < 4; ++r) {
      const float inv = 1.0f / Lr[r];
      const size_t rowoff = (size_t)(q0 + w * 16 + 4 * lh + r) * DMODEL + head * 128;
#pragma unroll
      for (int vt = 0; vt < 8; ++vt)
        aout[rowoff + vt * 16 + lr] = f2bf(oacc[vt][r] * inv);
    }
  }
}

extern "C" void kernel_launch(void* const* d_in, const int* in_sizes, int n_in,
                              void* d_out, int out_size, void* d_ws, size_t ws_size,
                              hipStream_t stream) {
  (void)in_sizes; (void)n_in; (void)out_size; (void)ws_size;
  const float* x     = (const float*)d_in[0];
  const float* r_cos = (const float*)d_in[1];
  const float* r_sin = (const float*)d_in[2];
  const float* wnorm = (const float*)d_in[3];
  const float* wq    = (const float*)d_in[4];
  const float* wk    = (const float*)d_in[5];
  const float* wv    = (const float*)d_in[6];
  const float* wo    = (const float*)d_in[7];

  // ws layout (bf16 elems): bufA 8.39M | qkvb 10.49M | wT 25.17M | vtg 2.10M = 92.3MB
  unsigned short* bufA = (unsigned short*)d_ws;                  // h, later attn-out
  unsigned short* qkvb = bufA + (size_t)TOK * DMODEL;            // [2048][5120]
  unsigned short* wT   = qkvb + (size_t)TOK * QKV_LD;            // wqkv^T, later wo^T
  unsigned short* vtg  = wT + (size_t)6144 * DMODEL;             // V^T [1024][2048]

  // dynamic-LDS caps (idempotent, host-side; safe under graph capture)
  hipFuncSetAttribute((const void*)k_gemm_big<256, 192, 0>,
                      hipFuncAttributeMaxDynamicSharedMemorySize, 4 * (256 + 192) * 64);
  hipFuncSetAttribute((const void*)k_gemm_big<256, 128, 1>,
                      hipFuncAttributeMaxDynamicSharedMemorySize, 4 * (256 + 128) * 64);
  const int attn_lds = 4 * KVB * 128 * 2 + 4 * 16 * PS_LD * 2;   // 74752 B
  hipFuncSetAttribute((const void*)k_attn,
                      hipFuncAttributeMaxDynamicSharedMemorySize, attn_lds);

  k_rmsnorm<<<TOK, 256, 0, stream>>>(x, wnorm, bufA);
  k_wconvert<<<dim3(64, 64), 256, 0, stream>>>(wq, wT, DMODEL, 4096);
  k_wconvert<<<dim3(16, 64), 256, 0, stream>>>(wk, wT + (size_t)4096 * DMODEL, DMODEL, 1024);
  k_wconvert<<<dim3(16, 64), 256, 0, stream>>>(wv, wT + (size_t)5120 * DMODEL, DMODEL, 1024);
  k_gemm_big<256, 192, 0><<<dim3(256), 512, 4 * (256 + 192) * 64, stream>>>(
      bufA, wT, nullptr, qkvb, vtg, r_cos, r_sin, TOK, 6144, DMODEL);
  k_wconvert<<<dim3(64, 64), 256, 0, stream>>>(wo, wT, DMODEL, 4096);   // overlay: wo^T
  k_attn<<<dim3(16, 32), 256, attn_lds, stream>>>(qkvb, vtg, bufA);
  k_gemm_big<256, 128, 1><<<dim3(256), 512, 4 * (256 + 128) * 64, stream>>>(
      bufA, wT, x, d_out, nullptr, nullptr, nullptr, TOK, DMODEL, DMODEL);
}

// Round 8
// 309.603 us; speedup vs baseline: 1.1046x; 1.0523x over previous
//
#include <hip/hip_runtime.h>
#include <stdint.h>
#include <math.h>

#define TOK 2048
#define DMODEL 4096
#define QKV_LD 5120   // q(4096) | k(1024); V goes transposed to vtg
#define KVB 64
#define PS_LD 72      // 64 kv + 8 pad (P-tile LDS stride)

typedef __attribute__((ext_vector_type(8))) short short8;
typedef __attribute__((ext_vector_type(4))) short short4v;
typedef __attribute__((ext_vector_type(8))) __bf16 bf16x8;
typedef __attribute__((ext_vector_type(4))) float f32x4;

__device__ __forceinline__ unsigned short f2bf(float f) {
  unsigned u = __float_as_uint(f);
  u += 0x7fffu + ((u >> 16) & 1u);   // RNE
  return (unsigned short)(u >> 16);
}

__device__ __forceinline__ void gl16(const void* g, void* l) {
  __builtin_amdgcn_global_load_lds((__attribute__((address_space(1))) void*)g,
                                   (__attribute__((address_space(3))) void*)l,
                                   16, 0, 0);
}

__device__ __forceinline__ f32x4 mfma16(short8 a, short8 b, f32x4 c) {
  return __builtin_amdgcn_mfma_f32_16x16x32_bf16(__builtin_bit_cast(bf16x8, a),
                                                 __builtin_bit_cast(bf16x8, b),
                                                 c, 0, 0, 0);
}

__device__ __forceinline__ float fexp2(float x) {
  float r;
  asm("v_exp_f32 %0, %1" : "=v"(r) : "v"(x));
  return r;
}

template <int N>
__device__ __forceinline__ void waitvm() {
  if constexpr (N == 0) asm volatile("s_waitcnt vmcnt(0)" ::: "memory");
  else if constexpr (N == 3) asm volatile("s_waitcnt vmcnt(3)" ::: "memory");
  else if constexpr (N == 4) asm volatile("s_waitcnt vmcnt(4)" ::: "memory");
  else if constexpr (N == 8) asm volatile("s_waitcnt vmcnt(8)" ::: "memory");
  else static_assert(N == 0 || N == 3 || N == 4 || N == 8, "add literal");
}

// ---------------- RMSNorm: fp32 x -> bf16 h ----------------
__global__ __launch_bounds__(256) void k_rmsnorm(const float* __restrict__ x,
                                                 const float* __restrict__ w,
                                                 unsigned short* __restrict__ h) {
  const int row = blockIdx.x;
  const float* xr = x + (size_t)row * DMODEL;
  float4 v[4];
  float ss = 0.f;
#pragma unroll
  for (int i = 0; i < 4; ++i) {
    v[i] = *(const float4*)(xr + threadIdx.x * 4 + i * 1024);
    ss += v[i].x * v[i].x + v[i].y * v[i].y + v[i].z * v[i].z + v[i].w * v[i].w;
  }
#pragma unroll
  for (int m = 1; m < 64; m <<= 1) ss += __shfl_xor(ss, m, 64);
  __shared__ float ws4[4];
  if ((threadIdx.x & 63) == 0) ws4[threadIdx.x >> 6] = ss;
  __syncthreads();
  const float scale = rsqrtf((ws4[0] + ws4[1] + ws4[2] + ws4[3]) * (1.0f / DMODEL) + 1e-5f);
  unsigned short* hr = h + (size_t)row * DMODEL;
#pragma unroll
  for (int i = 0; i < 4; ++i) {
    int col = threadIdx.x * 4 + i * 1024;
    float4 wv = *(const float4*)(w + col);
    uint2 o;
    o.x = (unsigned)f2bf(v[i].x * scale * wv.x) | ((unsigned)f2bf(v[i].y * scale * wv.y) << 16);
    o.y = (unsigned)f2bf(v[i].z * scale * wv.z) | ((unsigned)f2bf(v[i].w * scale * wv.w) << 16);
    *(uint2*)(hr + col) = o;
  }
}

// ------- Weight convert+transpose: W[K][N] fp32 -> WT[N][K] bf16 -------
__global__ __launch_bounds__(256) void k_wconvert(const float* __restrict__ W,
                                                  unsigned short* __restrict__ WT,
                                                  int K, int N) {
  __shared__ unsigned short tile[64][65];
  const int n0 = blockIdx.x * 64, k0 = blockIdx.y * 64;
  const int t = threadIdx.x;
  {
    const int r = t >> 2, c0 = (t & 3) * 16;
    const float* src = W + (size_t)(k0 + r) * N + n0 + c0;
#pragma unroll
    for (int i = 0; i < 4; ++i) {
      float4 f = *(const float4*)(src + i * 4);
      tile[r][c0 + i * 4 + 0] = f2bf(f.x);
      tile[r][c0 + i * 4 + 1] = f2bf(f.y);
      tile[r][c0 + i * 4 + 2] = f2bf(f.z);
      tile[r][c0 + i * 4 + 3] = f2bf(f.w);
    }
  }
  __syncthreads();
  {
    const int n = t >> 2, c0 = (t & 3) * 16;
    unsigned short* dst = WT + (size_t)(n0 + n) * K + k0 + c0;
    unsigned short v[16];
#pragma unroll
    for (int i = 0; i < 16; ++i) v[i] = tile[c0 + i][n];
    uint4 o0, o1;
    o0.x = v[0] | ((unsigned)v[1] << 16);  o0.y = v[2] | ((unsigned)v[3] << 16);
    o0.z = v[4] | ((unsigned)v[5] << 16);  o0.w = v[6] | ((unsigned)v[7] << 16);
    o1.x = v[8] | ((unsigned)v[9] << 16);  o1.y = v[10] | ((unsigned)v[11] << 16);
    o1.z = v[12] | ((unsigned)v[13] << 16); o1.w = v[14] | ((unsigned)v[15] << 16);
    *(uint4*)dst = o0;
    *(uint4*)(dst + 8) = o1;
  }
}

// ======== Counted 2-barrier GEMM: A[M][K] x BT[N][K] -> C[M][N] ========
// 8 waves (2M x 4N), BK=64, double-buffered LDS, XOR-swizzled tiles.
// Per K-tile: P0 {stage h0 -> vmcnt(H0) -> barrier -> reads -> MFMA},
// P1 {stage h1 || reads/MFMA}, P2 {reads/MFMA}, P3 {reads -> lgkmcnt(0)
// -> barrier -> MFMA}. Loads never drained mid-loop.
__device__ __forceinline__ short8 rdfrag(const unsigned short* buf, int row, int kc) {
  return *(const short8*)((const char*)buf + row * 128 + ((kc ^ (row & 7)) << 4));
}

template <int BM, int BN, int HALF>
__device__ __forceinline__ void stage_half(const unsigned short* __restrict__ A,
                                           const unsigned short* __restrict__ BT,
                                           unsigned short* __restrict__ buf,
                                           int m0, int n0, int K, int kt, int tid) {
  constexpr int LA = BM / 64, LB = BN / 64;
  constexpr int H0A = LA / 2, H0B = (LB + 1) / 2;
  constexpr int A0 = HALF ? H0A : 0, A1 = HALF ? LA : H0A;
  constexpr int B0 = HALF ? H0B : 0, B1 = HALF ? LB : H0B;
  unsigned short* bbuf = buf + BM * 64;
#pragma unroll
  for (int i = A0; i < A1; ++i) {
    const int s = i * 512 + tid, row = s >> 3, ch = s & 7;
    gl16(A + (size_t)(m0 + row) * K + kt + ((ch ^ (row & 7)) << 3), (char*)buf + s * 16);
  }
#pragma unroll
  for (int i = B0; i < B1; ++i) {
    const int s = i * 512 + tid, row = s >> 3, ch = s & 7;
    gl16(BT + (size_t)(n0 + row) * K + kt + ((ch ^ (row & 7)) << 3), (char*)bbuf + s * 16);
  }
}

// MODE=0: qkv epilogue with fused RoPE (cols<5120 -> roped bf16 qkvb;
//         cols>=5120 -> vtg transposed).  MODE=1: fp32 C = acc + resid.
// Panel grid is (8 m) x (32 n) for both GEMMs; each XCD owns a 4m x 8n chunk.
template <int BM, int BN, int MODE>
__global__ __launch_bounds__(512, 2) void k_gemm_big(const unsigned short* __restrict__ A,
                                                     const unsigned short* __restrict__ BT,
                                                     const float* __restrict__ resid,
                                                     void* __restrict__ Cout,
                                                     unsigned short* __restrict__ vtg,
                                                     const float* __restrict__ rc,
                                                     const float* __restrict__ rs,
                                                     int M, int N, int K) {
  extern __shared__ __align__(16) unsigned short lds[];
  constexpr int MREP = BM / 32;            // 8 (two halves of 4)
  constexpr int NREP = BN / 64;            // 3 (qkv) / 2 (out)
  constexpr int TILE = (BM + BN) * 64;
  constexpr int LA = BM / 64, LB = BN / 64;
  constexpr int H0 = LA / 2 + (LB + 1) / 2;   // loads issued in P0

  const int tid = threadIdx.x, lane = tid & 63;
  const int w = tid >> 6, wm = w >> 2, wn = w & 3;
  const int lr = lane & 15, lh = lane >> 4;

  // 2-D XCD chunking over the 8x32 panel grid (bijective)
  const int wg0 = blockIdx.x;
  const int xcd = wg0 & 7, l = wg0 >> 3;
  const int m0 = (((xcd >> 2) << 2) + (l >> 3)) * BM;
  const int n0 = (((xcd & 3) << 3) + (l & 7)) * BN;

  const f32x4 zf = {0.f, 0.f, 0.f, 0.f};
  f32x4 acc[MREP][NREP];
#pragma unroll
  for (int i = 0; i < MREP; ++i) {
#pragma unroll
    for (int j = 0; j < NREP; ++j) acc[i][j] = zf;
  }

  const int arow0 = wm * (BM / 2);
  const int brow0 = wn * (BN / 4);
  const int NT = K >> 6;
  int cur = 0;

  stage_half<BM, BN, 0>(A, BT, lds, m0, n0, K, 0, tid);
  stage_half<BM, BN, 1>(A, BT, lds, m0, n0, K, 0, tid);

  for (int t = 0; t < NT; ++t) {
    const unsigned short* abuf = lds + cur * TILE;
    const unsigned short* bbuf = abuf + BM * 64;
    unsigned short* nbuf = lds + (cur ^ 1) * TILE;
    const bool pre = (t + 1 < NT);
    const int ktn = (t + 1) << 6;

    short8 bfr[NREP], afr[4];
    // ---- P0: stage h0(t+1), counted wait for tile t, barrier, kk0 h0
    if (pre) {
      stage_half<BM, BN, 0>(A, BT, nbuf, m0, n0, K, ktn, tid);
      waitvm<H0>();
    } else {
      waitvm<0>();
    }
    __builtin_amdgcn_s_barrier();
#pragma unroll
    for (int nr = 0; nr < NREP; ++nr) bfr[nr] = rdfrag(bbuf, brow0 + nr * 16 + lr, lh);
#pragma unroll
    for (int mi = 0; mi < 4; ++mi) afr[mi] = rdfrag(abuf, arow0 + mi * 16 + lr, lh);
    __builtin_amdgcn_s_setprio(1);
#pragma unroll
    for (int mi = 0; mi < 4; ++mi) {
#pragma unroll
      for (int nr = 0; nr < NREP; ++nr)
        acc[mi][nr] = mfma16(afr[mi], bfr[nr], acc[mi][nr]);
    }
    __builtin_amdgcn_s_setprio(0);
    // ---- P1: stage h1(t+1) || kk0 h1
    if (pre) stage_half<BM, BN, 1>(A, BT, nbuf, m0, n0, K, ktn, tid);
#pragma unroll
    for (int mi = 0; mi < 4; ++mi) afr[mi] = rdfrag(abuf, arow0 + (4 + mi) * 16 + lr, lh);
    __builtin_amdgcn_s_setprio(1);
#pragma unroll
    for (int mi = 0; mi < 4; ++mi) {
#pragma unroll
      for (int nr = 0; nr < NREP; ++nr)
        acc[4 + mi][nr] = mfma16(afr[mi], bfr[nr], acc[4 + mi][nr]);
    }
    __builtin_amdgcn_s_setprio(0);
    // ---- P2: kk1 h0
#pragma unroll
    for (int nr = 0; nr < NREP; ++nr) bfr[nr] = rdfrag(bbuf, brow0 + nr * 16 + lr, 4 + lh);
#pragma unroll
    for (int mi = 0; mi < 4; ++mi) afr[mi] = rdfrag(abuf, arow0 + mi * 16 + lr, 4 + lh);
    __builtin_amdgcn_s_setprio(1);
#pragma unroll
    for (int mi = 0; mi < 4; ++mi) {
#pragma unroll
      for (int nr = 0; nr < NREP; ++nr)
        acc[mi][nr] = mfma16(afr[mi], bfr[nr], acc[mi][nr]);
    }
    __builtin_amdgcn_s_setprio(0);
    // ---- P3: kk1 h1; all reads done -> barrier (frees buf[cur]) -> MFMA
#pragma unroll
    for (int mi = 0; mi < 4; ++mi) afr[mi] = rdfrag(abuf, arow0 + (4 + mi) * 16 + lr, 4 + lh);
    asm volatile("s_waitcnt lgkmcnt(0)" ::: "memory");
    __builtin_amdgcn_s_barrier();
    __builtin_amdgcn_s_setprio(1);
#pragma unroll
    for (int mi = 0; mi < 4; ++mi) {
#pragma unroll
      for (int nr = 0; nr < NREP; ++nr)
        acc[4 + mi][nr] = mfma16(afr[mi], bfr[nr], acc[4 + mi][nr]);
    }
    __builtin_amdgcn_s_setprio(0);
    cur ^= 1;
  }

  // ---- epilogue: C row = 4*lh + r, col = lr within each 16x16 tile
#pragma unroll
  for (int ai = 0; ai < MREP; ++ai) {
#pragma unroll
    for (int ni = 0; ni < NREP; ++ni) {
      const int colg = n0 + wn * (BN / 4) + ni * 16 + lr;
      const int rowg0 = m0 + wm * (BM / 2) + ai * 16 + 4 * lh;
      if (MODE == 1) {
#pragma unroll
        for (int r = 0; r < 4; ++r)
          ((float*)Cout)[(size_t)(rowg0 + r) * N + colg] =
              acc[ai][ni][r] + resid[(size_t)(rowg0 + r) * N + colg];
      } else if (colg >= 5120) {
        short4v o;
#pragma unroll
        for (int r = 0; r < 4; ++r) o[r] = (short)f2bf(acc[ai][ni][r]);
        *(short4v*)(vtg + (size_t)(colg - 5120) * TOK + rowg0) = o;
      } else {
        // fused RoPE: pair (even,odd) cols live in adjacent lanes
        const int d = colg & 127;
#pragma unroll
        for (int r = 0; r < 4; ++r) {
          const int row = rowg0 + r;
          const float v = acc[ai][ni][r];
          const float p = __shfl_xor(v, 1, 64);
          const float c = rc[row * 128 + d];
          const float s = rs[row * 128 + d];
          const float y = (lr & 1) ? fmaf(p, s, v * c) : fmaf(-p, s, v * c);
          ((unsigned short*)Cout)[(size_t)row * QKV_LD + colg] = f2bf(y);
        }
      }
    }
  }
}

// ---------------- Flash attention, causal, GQA ----------------
// grid (16 pairs, 32 heads); block = 4 waves x 16 q-rows = 64 q-rows.
// Double-buffered K/V staging with counted vmcnt(8); 2 barriers per KV-tile.
// Softmax: mask only diagonal tile; per-lane deferred L; defer-max skip (THR=8).
__global__ __launch_bounds__(256) void k_attn(const unsigned short* __restrict__ qkv,
                                              const unsigned short* __restrict__ vtg,
                                              unsigned short* __restrict__ aout) {
  extern __shared__ __align__(16) unsigned short sm[];
  unsigned short* const KsB = sm;                    // [2][KVB*128]
  unsigned short* const VtB = sm + 2 * KVB * 128;    // [2][128*KVB]
  unsigned short* const Ps = sm + 4 * KVB * 128;     // [4][16*PS_LD]
  const int head = blockIdx.y;
  const int hkv = head >> 2;
  const int tid = threadIdx.x, lane = tid & 63, w = tid >> 6;
  const int lr = lane & 15, lh = lane >> 4;
  const float scale2 = 0.08838834764831845f * 1.44269504088896340736f;  // /sqrt(128)*log2(e)
  const f32x4 zf = {0.f, 0.f, 0.f, 0.f};

  for (int half = 0; half < 2; ++half) {
    const int qt = half ? (31 - blockIdx.x) : blockIdx.x;
    const int q0 = qt * 64;

    short8 qf[4];
    {
      const unsigned short* qbase = qkv + (size_t)(q0 + w * 16 + lr) * QKV_LD + head * 128;
#pragma unroll
      for (int kd = 0; kd < 4; ++kd) qf[kd] = *(const short8*)(qbase + kd * 32 + lh * 8);
    }
    f32x4 oacc[8];
#pragma unroll
    for (int vt = 0; vt < 8; ++vt) oacc[vt] = zf;
    float Mr[4], Lp[4];
#pragma unroll
    for (int r = 0; r < 4; ++r) { Mr[r] = -INFINITY; Lp[r] = 0.f; }

    const int nt = qt + 1;
    int cur = 0;

    // prologue: stage tile 0 into buffer 0 (8 gl16 per thread)
    {
#pragma unroll
      for (int c = 0; c < 4; ++c) {
        const int s = c * 256 + w * 64 + lane;
        const int row = s >> 4, cp = s & 15;
        gl16(qkv + (size_t)row * QKV_LD + 4096 + hkv * 128 + ((cp ^ (row & 7)) * 8),
             (char*)KsB + (c * 256 + w * 64) * 16);
      }
#pragma unroll
      for (int c = 0; c < 4; ++c) {
        const int s = c * 256 + w * 64 + lane;
        const int row = s >> 3, cp = s & 7;
        gl16(vtg + (size_t)(hkv * 128 + row) * TOK + ((cp ^ (row & 7)) * 8),
             (char*)VtB + (c * 256 + w * 64) * 16);
      }
    }

    for (int t = 0; t < nt; ++t) {
      const unsigned short* Ks = KsB + cur * (KVB * 128);
      const unsigned short* Vt = VtB + cur * (128 * KVB);
      const int kv0 = t * KVB;
      // prefetch tile t+1 into the other buffer, counted wait for tile t
      if (t + 1 < nt) {
        unsigned short* Ksn = KsB + (cur ^ 1) * (KVB * 128);
        unsigned short* Vtn = VtB + (cur ^ 1) * (128 * KVB);
        const int kvn = (t + 1) * KVB;
#pragma unroll
        for (int c = 0; c < 4; ++c) {
          const int s = c * 256 + w * 64 + lane;
          const int row = s >> 4, cp = s & 15;
          gl16(qkv + (size_t)(kvn + row) * QKV_LD + 4096 + hkv * 128 + ((cp ^ (row & 7)) * 8),
               (char*)Ksn + (c * 256 + w * 64) * 16);
        }
#pragma unroll
        for (int c = 0; c < 4; ++c) {
          const int s = c * 256 + w * 64 + lane;
          const int row = s >> 3, cp = s & 7;
          gl16(vtg + (size_t)(hkv * 128 + row) * TOK + kvn + ((cp ^ (row & 7)) * 8),
               (char*)Vtn + (c * 256 + w * 64) * 16);
        }
        waitvm<8>();
      } else {
        waitvm<0>();
      }
      __builtin_amdgcn_s_barrier();

      // QK^T: S[16 q][64 kv] per wave
      f32x4 sacc[4];
#pragma unroll
      for (int ct = 0; ct < 4; ++ct) {
        sacc[ct] = zf;
        const int row = ct * 16 + lr;
#pragma unroll
        for (int kd = 0; kd < 4; ++kd) {
          const short8 kf = *(const short8*)((const char*)Ks + row * 256 +
                                             (((kd * 4 + lh) ^ (row & 7)) * 16));
          sacc[ct] = mfma16(qf[kd], kf, sacc[ct]);
        }
      }

      // softmax: scale, (diag-only) mask, max-reduce; defer-max skip; exp2
      const bool diag = (t == qt);
      float sv[4][4], gmax[4];
#pragma unroll
      for (int r = 0; r < 4; ++r) {
        float s0 = sacc[0][r] * scale2;
        float s1 = sacc[1][r] * scale2;
        float s2 = sacc[2][r] * scale2;
        float s3 = sacc[3][r] * scale2;
        if (diag) {
          const int qrow = q0 + w * 16 + 4 * lh + r;
          if (kv0 + lr > qrow) s0 = -INFINITY;
          if (kv0 + 16 + lr > qrow) s1 = -INFINITY;
          if (kv0 + 32 + lr > qrow) s2 = -INFINITY;
          if (kv0 + 48 + lr > qrow) s3 = -INFINITY;
        }
        float tmax = fmaxf(fmaxf(s0, s1), fmaxf(s2, s3));
        tmax = fmaxf(tmax, __shfl_xor(tmax, 1, 16));
        tmax = fmaxf(tmax, __shfl_xor(tmax, 2, 16));
        tmax = fmaxf(tmax, __shfl_xor(tmax, 4, 16));
        tmax = fmaxf(tmax, __shfl_xor(tmax, 8, 16));
        gmax[r] = tmax;
        sv[r][0] = s0; sv[r][1] = s1; sv[r][2] = s2; sv[r][3] = s3;
      }
      const int cond = (gmax[0] <= Mr[0] + 8.f) && (gmax[1] <= Mr[1] + 8.f) &&
                       (gmax[2] <= Mr[2] + 8.f) && (gmax[3] <= Mr[3] + 8.f);
      if (!__all(cond)) {
        float scv[4];
#pragma unroll
        for (int r = 0; r < 4; ++r) {
          const float mnew = fmaxf(Mr[r], gmax[r]);
          scv[r] = fexp2(Mr[r] - mnew);
          Mr[r] = mnew;
          Lp[r] *= scv[r];
        }
#pragma unroll
        for (int vt = 0; vt < 8; ++vt) {
#pragma unroll
          for (int r = 0; r < 4; ++r) oacc[vt][r] *= scv[r];
        }
      }
      float pv[4][4];
#pragma unroll
      for (int r = 0; r < 4; ++r) {
        const float p0 = fexp2(sv[r][0] - Mr[r]);
        const float p1 = fexp2(sv[r][1] - Mr[r]);
        const float p2 = fexp2(sv[r][2] - Mr[r]);
        const float p3 = fexp2(sv[r][3] - Mr[r]);
        Lp[r] += (p0 + p1) + (p2 + p3);   // per-lane partial; reduced at epilogue
        pv[r][0] = p0; pv[r][1] = p1; pv[r][2] = p2; pv[r][3] = p3;
      }

      // P -> per-wave LDS (stride 72 >= 64 kv), then PV
      unsigned short* pw = Ps + w * (16 * PS_LD);
#pragma unroll
      for (int r = 0; r < 4; ++r) {
#pragma unroll
        for (int ct = 0; ct < 4; ++ct)
          pw[(4 * lh + r) * PS_LD + ct * 16 + lr] = f2bf(pv[r][ct]);
      }
      asm volatile("s_waitcnt lgkmcnt(0)" ::: "memory");
      short8 pf[2];
      pf[0] = *(const short8*)(pw + lr * PS_LD + lh * 8);
      pf[1] = *(const short8*)(pw + lr * PS_LD + 32 + lh * 8);
      __builtin_amdgcn_s_setprio(1);
#pragma unroll
      for (int vt = 0; vt < 8; ++vt) {
        const int d = vt * 16 + lr;
#pragma unroll
        for (int kb = 0; kb < 2; ++kb) {
          const short8 vf = *(const short8*)((const char*)Vt + d * 128 +
                                             (((kb * 4 + lh) ^ (lr & 7)) * 16));
          oacc[vt] = mfma16(pf[kb], vf, oacc[vt]);
        }
      }
      __builtin_amdgcn_s_setprio(0);
      // all reads of buf[cur] done -> safe for next tile's stage overwrite
      asm volatile("s_waitcnt lgkmcnt(0)" ::: "memory");
      __builtin_amdgcn_s_barrier();
      cur ^= 1;
    }

    // epilogue for this q-tile: reduce deferred L partials, normalize, store
#pragma unroll
    for (int r = 0; r < 4; ++r) {
      float Ls = Lp[r];
      Ls += __shfl_xor(Ls, 1, 16);
      Ls += __shfl_xor(Ls, 2, 16);
      Ls += __shfl_xor(Ls, 4, 16);
      Ls += __shfl_xor(Ls, 8, 16);
      const float inv = 1.0f / Ls;
      const size_t rowoff = (size_t)(q0 + w * 16 + 4 * lh + r) * DMODEL + head * 128;
#pragma unroll
      for (int vt = 0; vt < 8; ++vt)
        aout[rowoff + vt * 16 + lr] = f2bf(oacc[vt][r] * inv);
    }
  }
}

extern "C" void kernel_launch(void* const* d_in, const int* in_sizes, int n_in,
                              void* d_out, int out_size, void* d_ws, size_t ws_size,
                              hipStream_t stream) {
  (void)in_sizes; (void)n_in; (void)out_size; (void)ws_size;
  const float* x     = (const float*)d_in[0];
  const float* r_cos = (const float*)d_in[1];
  const float* r_sin = (const float*)d_in[2];
  const float* wnorm = (const float*)d_in[3];
  const float* wq    = (const float*)d_in[4];
  const float* wk    = (const float*)d_in[5];
  const float* wv    = (const float*)d_in[6];
  const float* wo    = (const float*)d_in[7];

  // ws layout (bf16 elems): bufA 8.39M | qkvb 10.49M | wT 25.17M | vtg 2.10M = 92.3MB
  unsigned short* bufA = (unsigned short*)d_ws;                  // h, later attn-out
  unsigned short* qkvb = bufA + (size_t)TOK * DMODEL;            // [2048][5120]
  unsigned short* wT   = qkvb + (size_t)TOK * QKV_LD;            // wqkv^T, later wo^T
  unsigned short* vtg  = wT + (size_t)6144 * DMODEL;             // V^T [1024][2048]

  // dynamic-LDS caps (idempotent, host-side; safe under graph capture)
  hipFuncSetAttribute((const void*)k_gemm_big<256, 192, 0>,
                      hipFuncAttributeMaxDynamicSharedMemorySize, 4 * (256 + 192) * 64);
  hipFuncSetAttribute((const void*)k_gemm_big<256, 128, 1>,
                      hipFuncAttributeMaxDynamicSharedMemorySize, 4 * (256 + 128) * 64);
  const int attn_lds = 4 * KVB * 128 * 2 + 4 * 16 * PS_LD * 2;   // 74752 B
  hipFuncSetAttribute((const void*)k_attn,
                      hipFuncAttributeMaxDynamicSharedMemorySize, attn_lds);

  k_rmsnorm<<<TOK, 256, 0, stream>>>(x, wnorm, bufA);
  k_wconvert<<<dim3(64, 64), 256, 0, stream>>>(wq, wT, DMODEL, 4096);
  k_wconvert<<<dim3(16, 64), 256, 0, stream>>>(wk, wT + (size_t)4096 * DMODEL, DMODEL, 1024);
  k_wconvert<<<dim3(16, 64), 256, 0, stream>>>(wv, wT + (size_t)5120 * DMODEL, DMODEL, 1024);
  k_gemm_big<256, 192, 0><<<dim3(256), 512, 4 * (256 + 192) * 64, stream>>>(
      bufA, wT, nullptr, qkvb, vtg, r_cos, r_sin, TOK, 6144, DMODEL);
  k_wconvert<<<dim3(64, 64), 256, 0, stream>>>(wo, wT, DMODEL, 4096);   // overlay: wo^T
  k_attn<<<dim3(16, 32), 256, attn_lds, stream>>>(qkvb, vtg, bufA);
  k_gemm_big<256, 128, 1><<<dim3(256), 512, 4 * (256 + 128) * 64, stream>>>(
      bufA, wT, x, d_out, nullptr, nullptr, nullptr, TOK, DMODEL, DMODEL);
}

// Round 9
// 309.018 us; speedup vs baseline: 1.1066x; 1.0019x over previous
//
#include <hip/hip_runtime.h>
#include <stdint.h>
#include <math.h>

#define TOK 2048
#define DMODEL 4096
#define QKV_LD 5120   // q(4096) | k(1024); V goes transposed to vtg
#define KVB 64
#define PS_LD 72      // 64 kv + 8 pad (P-tile LDS stride)

typedef __attribute__((ext_vector_type(8))) short short8;
typedef __attribute__((ext_vector_type(4))) short short4v;
typedef __attribute__((ext_vector_type(8))) __bf16 bf16x8;
typedef __attribute__((ext_vector_type(4))) float f32x4;

__device__ __forceinline__ unsigned short f2bf(float f) {
  unsigned u = __float_as_uint(f);
  u += 0x7fffu + ((u >> 16) & 1u);   // RNE
  return (unsigned short)(u >> 16);
}

__device__ __forceinline__ void gl16(const void* g, void* l) {
  __builtin_amdgcn_global_load_lds((__attribute__((address_space(1))) void*)g,
                                   (__attribute__((address_space(3))) void*)l,
                                   16, 0, 0);
}

__device__ __forceinline__ f32x4 mfma16(short8 a, short8 b, f32x4 c) {
  return __builtin_amdgcn_mfma_f32_16x16x32_bf16(__builtin_bit_cast(bf16x8, a),
                                                 __builtin_bit_cast(bf16x8, b),
                                                 c, 0, 0, 0);
}

__device__ __forceinline__ float fexp2(float x) {
  float r;
  asm("v_exp_f32 %0, %1" : "=v"(r) : "v"(x));
  return r;
}

__device__ __forceinline__ void waitvm0() {
  asm volatile("s_waitcnt vmcnt(0)" ::: "memory");
}

// ---------------- RMSNorm: fp32 x -> bf16 h ----------------
__global__ __launch_bounds__(256) void k_rmsnorm(const float* __restrict__ x,
                                                 const float* __restrict__ w,
                                                 unsigned short* __restrict__ h) {
  const int row = blockIdx.x;
  const float* xr = x + (size_t)row * DMODEL;
  float4 v[4];
  float ss = 0.f;
#pragma unroll
  for (int i = 0; i < 4; ++i) {
    v[i] = *(const float4*)(xr + threadIdx.x * 4 + i * 1024);
    ss += v[i].x * v[i].x + v[i].y * v[i].y + v[i].z * v[i].z + v[i].w * v[i].w;
  }
#pragma unroll
  for (int m = 1; m < 64; m <<= 1) ss += __shfl_xor(ss, m, 64);
  __shared__ float ws4[4];
  if ((threadIdx.x & 63) == 0) ws4[threadIdx.x >> 6] = ss;
  __syncthreads();
  const float scale = rsqrtf((ws4[0] + ws4[1] + ws4[2] + ws4[3]) * (1.0f / DMODEL) + 1e-5f);
  unsigned short* hr = h + (size_t)row * DMODEL;
#pragma unroll
  for (int i = 0; i < 4; ++i) {
    int col = threadIdx.x * 4 + i * 1024;
    float4 wv = *(const float4*)(w + col);
    uint2 o;
    o.x = (unsigned)f2bf(v[i].x * scale * wv.x) | ((unsigned)f2bf(v[i].y * scale * wv.y) << 16);
    o.y = (unsigned)f2bf(v[i].z * scale * wv.z) | ((unsigned)f2bf(v[i].w * scale * wv.w) << 16);
    *(uint2*)(hr + col) = o;
  }
}

// ------- Weight convert+transpose: W[K][N] fp32 -> WT[N][K] bf16 -------
__global__ __launch_bounds__(256) void k_wconvert(const float* __restrict__ W,
                                                  unsigned short* __restrict__ WT,
                                                  int K, int N) {
  __shared__ unsigned short tile[64][65];
  const int n0 = blockIdx.x * 64, k0 = blockIdx.y * 64;
  const int t = threadIdx.x;
  {
    const int r = t >> 2, c0 = (t & 3) * 16;
    const float* src = W + (size_t)(k0 + r) * N + n0 + c0;
#pragma unroll
    for (int i = 0; i < 4; ++i) {
      float4 f = *(const float4*)(src + i * 4);
      tile[r][c0 + i * 4 + 0] = f2bf(f.x);
      tile[r][c0 + i * 4 + 1] = f2bf(f.y);
      tile[r][c0 + i * 4 + 2] = f2bf(f.z);
      tile[r][c0 + i * 4 + 3] = f2bf(f.w);
    }
  }
  __syncthreads();
  {
    const int n = t >> 2, c0 = (t & 3) * 16;
    unsigned short* dst = WT + (size_t)(n0 + n) * K + k0 + c0;
    unsigned short v[16];
#pragma unroll
    for (int i = 0; i < 16; ++i) v[i] = tile[c0 + i][n];
    uint4 o0, o1;
    o0.x = v[0] | ((unsigned)v[1] << 16);  o0.y = v[2] | ((unsigned)v[3] << 16);
    o0.z = v[4] | ((unsigned)v[5] << 16);  o0.w = v[6] | ((unsigned)v[7] << 16);
    o1.x = v[8] | ((unsigned)v[9] << 16);  o1.y = v[10] | ((unsigned)v[11] << 16);
    o1.z = v[12] | ((unsigned)v[13] << 16); o1.w = v[14] | ((unsigned)v[15] << 16);
    *(uint4*)dst = o0;
    *(uint4*)(dst + 8) = o1;
  }
}

// ======== Single-barrier pipelined GEMM: A[M][K] x BT[N][K] -> C[M][N] ========
// 8 waves, BK=64, double-buffered LDS, XOR-swizzled tiles. Per K-tile:
// waitvm(0) [stage(t) is a full tile old -> no stall] -> s_barrier ->
// issue stage(t+1) into buf[cur^1] -> 4 {read,MFMA} phases. Hazard proof:
// stage(t+1) overwrites the buffer read in tile t-1; all waves' t-1 reads
// retired (MFMA-consumed) before they reached barrier(t); issue is fenced
// after the barrier by sched_barrier(0).
__device__ __forceinline__ short8 rdfrag(const unsigned short* buf, int row, int kc) {
  return *(const short8*)((const char*)buf + row * 128 + ((kc ^ (row & 7)) << 4));
}

template <int BM, int BN>
__device__ __forceinline__ void stage_tile(const unsigned short* __restrict__ A,
                                           const unsigned short* __restrict__ BT,
                                           unsigned short* __restrict__ buf,
                                           int m0, int n0, int K, int kt, int tid) {
  constexpr int LA = BM / 64, LB = BN / 64;
  unsigned short* bbuf = buf + BM * 64;
#pragma unroll
  for (int i = 0; i < LA; ++i) {
    const int s = i * 512 + tid, row = s >> 3, ch = s & 7;
    gl16(A + (size_t)(m0 + row) * K + kt + ((ch ^ (row & 7)) << 3), (char*)buf + s * 16);
  }
#pragma unroll
  for (int i = 0; i < LB; ++i) {
    const int s = i * 512 + tid, row = s >> 3, ch = s & 7;
    gl16(BT + (size_t)(n0 + row) * K + kt + ((ch ^ (row & 7)) << 3), (char*)bbuf + s * 16);
  }
}

// MODE=0: qkv epilogue with fused RoPE (cols<5120 -> roped bf16 qkvb;
//         cols>=5120 -> vtg transposed).  MODE=1: fp32 C = acc + resid.
// 2-D XCD chunking over the (M/BM) x (N/BN) panel grid, nwg=256, bijective.
template <int BM, int BN, int MODE, int LOGN>
__global__ __launch_bounds__(512, 2) void k_gemm_big(const unsigned short* __restrict__ A,
                                                     const unsigned short* __restrict__ BT,
                                                     const float* __restrict__ resid,
                                                     void* __restrict__ Cout,
                                                     unsigned short* __restrict__ vtg,
                                                     const float* __restrict__ rc,
                                                     const float* __restrict__ rs,
                                                     int M, int N, int K) {
  extern __shared__ __align__(16) unsigned short lds[];
  constexpr int MREP = BM / 32;            // m fragments per wave (wave_m = MREP*16)
  constexpr int NREP = BN / 64;            // n fragments per wave
  constexpr int MH = MREP / 2;
  constexpr int TILE = (BM + BN) * 64;

  const int tid = threadIdx.x, lane = tid & 63;
  const int w = tid >> 6, wm = w >> 2, wn = w & 3;
  const int lr = lane & 15, lh = lane >> 4;

  // XCD cell = (xcd>>2, xcd&3) over (2 m-cells x 4 n-cells); local l in cell.
  const int wg0 = blockIdx.x;
  const int xcd = wg0 & 7, l = wg0 >> 3;
  const int mch = (M / BM) >> 1;           // m-panels per cell
  const int m0 = ((xcd >> 2) * mch + (l >> LOGN)) * BM;
  const int n0 = ((xcd & 3) * (1 << LOGN) + (l & ((1 << LOGN) - 1))) * BN;

  const f32x4 zf = {0.f, 0.f, 0.f, 0.f};
  f32x4 acc[MREP][NREP];
#pragma unroll
  for (int i = 0; i < MREP; ++i) {
#pragma unroll
    for (int j = 0; j < NREP; ++j) acc[i][j] = zf;
  }

  const int arow0 = wm * (BM / 2);
  const int brow0 = wn * (BN / 4);
  const int NT = K >> 6;
  int cur = 0;

  stage_tile<BM, BN>(A, BT, lds, m0, n0, K, 0, tid);

  for (int t = 0; t < NT; ++t) {
    const unsigned short* abuf = lds + cur * TILE;
    const unsigned short* bbuf = abuf + BM * 64;
    waitvm0();                            // stage(t) landed (issued ~1 tile ago)
    __builtin_amdgcn_s_barrier();         // all waves: stage(t) visible, t-1 reads retired
    __builtin_amdgcn_sched_barrier(0);    // fence: nothing moves above the barrier
    if (t + 1 < NT)
      stage_tile<BM, BN>(A, BT, lds + (cur ^ 1) * TILE, m0, n0, K, (t + 1) << 6, tid);

#pragma unroll
    for (int kk = 0; kk < 2; ++kk) {
      short8 bfr[NREP];
#pragma unroll
      for (int nr = 0; nr < NREP; ++nr)
        bfr[nr] = rdfrag(bbuf, brow0 + nr * 16 + lr, kk * 4 + lh);
#pragma unroll
      for (int mh = 0; mh < 2; ++mh) {
        short8 afr[MH];
#pragma unroll
        for (int mi = 0; mi < MH; ++mi)
          afr[mi] = rdfrag(abuf, arow0 + (mh * MH + mi) * 16 + lr, kk * 4 + lh);
        __builtin_amdgcn_s_setprio(1);
#pragma unroll
        for (int mi = 0; mi < MH; ++mi) {
#pragma unroll
          for (int nr = 0; nr < NREP; ++nr)
            acc[mh * MH + mi][nr] = mfma16(afr[mi], bfr[nr], acc[mh * MH + mi][nr]);
        }
        __builtin_amdgcn_s_setprio(0);
      }
    }
    cur ^= 1;
  }

  // ---- epilogue: C row = 4*lh + r, col = lr within each 16x16 tile
#pragma unroll
  for (int ai = 0; ai < MREP; ++ai) {
#pragma unroll
    for (int ni = 0; ni < NREP; ++ni) {
      const int colg = n0 + wn * (BN / 4) + ni * 16 + lr;
      const int rowg0 = m0 + wm * (BM / 2) + ai * 16 + 4 * lh;
      if (MODE == 1) {
#pragma unroll
        for (int r = 0; r < 4; ++r)
          ((float*)Cout)[(size_t)(rowg0 + r) * N + colg] =
              acc[ai][ni][r] + resid[(size_t)(rowg0 + r) * N + colg];
      } else if (colg >= 5120) {
        short4v o;
#pragma unroll
        for (int r = 0; r < 4; ++r) o[r] = (short)f2bf(acc[ai][ni][r]);
        *(short4v*)(vtg + (size_t)(colg - 5120) * TOK + rowg0) = o;
      } else {
        // fused RoPE: pair (even,odd) cols live in adjacent lanes
        const int d = colg & 127;
#pragma unroll
        for (int r = 0; r < 4; ++r) {
          const int row = rowg0 + r;
          const float v = acc[ai][ni][r];
          const float p = __shfl_xor(v, 1, 64);
          const float c = rc[row * 128 + d];
          const float s = rs[row * 128 + d];
          const float y = (lr & 1) ? fmaf(p, s, v * c) : fmaf(-p, s, v * c);
          ((unsigned short*)Cout)[(size_t)row * QKV_LD + colg] = f2bf(y);
        }
      }
    }
  }
}

// ---------------- Flash attention, causal, GQA ----------------
// grid (16 pairs, 32 heads); block = 4 waves x 16 q-rows = 64 q-rows.
// Single-barrier double-buffered K/V pipeline (same hazard proof as GEMM).
// Softmax: mask only diagonal tile; per-lane deferred L; defer-max skip (THR=8).
__global__ __launch_bounds__(256) void k_attn(const unsigned short* __restrict__ qkv,
                                              const unsigned short* __restrict__ vtg,
                                              unsigned short* __restrict__ aout) {
  extern __shared__ __align__(16) unsigned short sm[];
  unsigned short* const KsB = sm;                    // [2][KVB*128]
  unsigned short* const VtB = sm + 2 * KVB * 128;    // [2][128*KVB]
  unsigned short* const Ps = sm + 4 * KVB * 128;     // [4][16*PS_LD]
  const int head = blockIdx.y;
  const int hkv = head >> 2;
  const int tid = threadIdx.x, lane = tid & 63, w = tid >> 6;
  const int lr = lane & 15, lh = lane >> 4;
  const float scale2 = 0.08838834764831845f * 1.44269504088896340736f;  // /sqrt(128)*log2(e)
  const f32x4 zf = {0.f, 0.f, 0.f, 0.f};

  auto stageKV = [&](int kvt, int buf) {
    unsigned short* Ksn = KsB + buf * (KVB * 128);
    unsigned short* Vtn = VtB + buf * (128 * KVB);
    const int kvn = kvt * KVB;
#pragma unroll
    for (int c = 0; c < 4; ++c) {
      const int s = c * 256 + w * 64 + lane;
      const int row = s >> 4, cp = s & 15;
      gl16(qkv + (size_t)(kvn + row) * QKV_LD + 4096 + hkv * 128 + ((cp ^ (row & 7)) * 8),
           (char*)Ksn + (c * 256 + w * 64) * 16);
    }
#pragma unroll
    for (int c = 0; c < 4; ++c) {
      const int s = c * 256 + w * 64 + lane;
      const int row = s >> 3, cp = s & 7;
      gl16(vtg + (size_t)(hkv * 128 + row) * TOK + kvn + ((cp ^ (row & 7)) * 8),
           (char*)Vtn + (c * 256 + w * 64) * 16);
    }
  };

  for (int half = 0; half < 2; ++half) {
    const int qt = half ? (31 - blockIdx.x) : blockIdx.x;
    const int q0 = qt * 64;

    short8 qf[4];
    {
      const unsigned short* qbase = qkv + (size_t)(q0 + w * 16 + lr) * QKV_LD + head * 128;
#pragma unroll
      for (int kd = 0; kd < 4; ++kd) qf[kd] = *(const short8*)(qbase + kd * 32 + lh * 8);
    }
    f32x4 oacc[8];
#pragma unroll
    for (int vt = 0; vt < 8; ++vt) oacc[vt] = zf;
    float Mr[4], Lp[4];
#pragma unroll
    for (int r = 0; r < 4; ++r) { Mr[r] = -INFINITY; Lp[r] = 0.f; }

    const int nt = qt + 1;
    int cur = 0;
    stageKV(0, 0);    // prologue (buffer 0 free: inter-half barrier below)

    for (int t = 0; t < nt; ++t) {
      const unsigned short* Ks = KsB + cur * (KVB * 128);
      const unsigned short* Vt = VtB + cur * (128 * KVB);
      const int kv0 = t * KVB;
      waitvm0();
      __builtin_amdgcn_s_barrier();
      __builtin_amdgcn_sched_barrier(0);
      if (t + 1 < nt) stageKV(t + 1, cur ^ 1);

      // QK^T: S[16 q][64 kv] per wave
      f32x4 sacc[4];
#pragma unroll
      for (int ct = 0; ct < 4; ++ct) {
        sacc[ct] = zf;
        const int row = ct * 16 + lr;
#pragma unroll
        for (int kd = 0; kd < 4; ++kd) {
          const short8 kf = *(const short8*)((const char*)Ks + row * 256 +
                                             (((kd * 4 + lh) ^ (row & 7)) * 16));
          sacc[ct] = mfma16(qf[kd], kf, sacc[ct]);
        }
      }

      // softmax: scale, (diag-only) mask, max-reduce; defer-max skip; exp2
      const bool diag = (t == qt);
      float sv[4][4], gmax[4];
#pragma unroll
      for (int r = 0; r < 4; ++r) {
        float s0 = sacc[0][r] * scale2;
        float s1 = sacc[1][r] * scale2;
        float s2 = sacc[2][r] * scale2;
        float s3 = sacc[3][r] * scale2;
        if (diag) {
          const int qrow = q0 + w * 16 + 4 * lh + r;
          if (kv0 + lr > qrow) s0 = -INFINITY;
          if (kv0 + 16 + lr > qrow) s1 = -INFINITY;
          if (kv0 + 32 + lr > qrow) s2 = -INFINITY;
          if (kv0 + 48 + lr > qrow) s3 = -INFINITY;
        }
        float tmax = fmaxf(fmaxf(s0, s1), fmaxf(s2, s3));
        tmax = fmaxf(tmax, __shfl_xor(tmax, 1, 16));
        tmax = fmaxf(tmax, __shfl_xor(tmax, 2, 16));
        tmax = fmaxf(tmax, __shfl_xor(tmax, 4, 16));
        tmax = fmaxf(tmax, __shfl_xor(tmax, 8, 16));
        gmax[r] = tmax;
        sv[r][0] = s0; sv[r][1] = s1; sv[r][2] = s2; sv[r][3] = s3;
      }
      const int cond = (gmax[0] <= Mr[0] + 8.f) && (gmax[1] <= Mr[1] + 8.f) &&
                       (gmax[2] <= Mr[2] + 8.f) && (gmax[3] <= Mr[3] + 8.f);
      if (!__all(cond)) {
        float scv[4];
#pragma unroll
        for (int r = 0; r < 4; ++r) {
          const float mnew = fmaxf(Mr[r], gmax[r]);
          scv[r] = fexp2(Mr[r] - mnew);
          Mr[r] = mnew;
          Lp[r] *= scv[r];
        }
#pragma unroll
        for (int vt = 0; vt < 8; ++vt) {
#pragma unroll
          for (int r = 0; r < 4; ++r) oacc[vt][r] *= scv[r];
        }
      }
      float pv[4][4];
#pragma unroll
      for (int r = 0; r < 4; ++r) {
        const float p0 = fexp2(sv[r][0] - Mr[r]);
        const float p1 = fexp2(sv[r][1] - Mr[r]);
        const float p2 = fexp2(sv[r][2] - Mr[r]);
        const float p3 = fexp2(sv[r][3] - Mr[r]);
        Lp[r] += (p0 + p1) + (p2 + p3);   // per-lane partial; reduced at epilogue
        pv[r][0] = p0; pv[r][1] = p1; pv[r][2] = p2; pv[r][3] = p3;
      }

      // P -> per-wave LDS (stride 72 >= 64 kv), then PV
      unsigned short* pw = Ps + w * (16 * PS_LD);
#pragma unroll
      for (int r = 0; r < 4; ++r) {
#pragma unroll
        for (int ct = 0; ct < 4; ++ct)
          pw[(4 * lh + r) * PS_LD + ct * 16 + lr] = f2bf(pv[r][ct]);
      }
      asm volatile("s_waitcnt lgkmcnt(0)" ::: "memory");
      short8 pf[2];
      pf[0] = *(const short8*)(pw + lr * PS_LD + lh * 8);
      pf[1] = *(const short8*)(pw + lr * PS_LD + 32 + lh * 8);
      __builtin_amdgcn_s_setprio(1);
#pragma unroll
      for (int vt = 0; vt < 8; ++vt) {
        const int d = vt * 16 + lr;
#pragma unroll
        for (int kb = 0; kb < 2; ++kb) {
          const short8 vf = *(const short8*)((const char*)Vt + d * 128 +
                                             (((kb * 4 + lh) ^ (lr & 7)) * 16));
          oacc[vt] = mfma16(pf[kb], vf, oacc[vt]);
        }
      }
      __builtin_amdgcn_s_setprio(0);
      cur ^= 1;
    }

    // epilogue for this q-tile: reduce deferred L partials, normalize, store
#pragma unroll
    for (int r = 0; r < 4; ++r) {
      float Ls = Lp[r];
      Ls += __shfl_xor(Ls, 1, 16);
      Ls += __shfl_xor(Ls, 2, 16);
      Ls += __shfl_xor(Ls, 4, 16);
      Ls += __shfl_xor(Ls, 8, 16);
      const float inv = 1.0f / Ls;
      const size_t rowoff = (size_t)(q0 + w * 16 + 4 * lh + r) * DMODEL + head * 128;
#pragma unroll
      for (int vt = 0; vt < 8; ++vt)
        aout[rowoff + vt * 16 + lr] = f2bf(oacc[vt][r] * inv);
    }
    // inter-half barrier: next half's prologue overwrites buffer 0; all
    // waves' reads of this half must be retired (MFMA-consumed) first.
    __builtin_amdgcn_s_barrier();
    __builtin_amdgcn_sched_barrier(0);
  }
}

extern "C" void kernel_launch(void* const* d_in, const int* in_sizes, int n_in,
                              void* d_out, int out_size, void* d_ws, size_t ws_size,
                              hipStream_t stream) {
  (void)in_sizes; (void)n_in; (void)out_size; (void)ws_size;
  const float* x     = (const float*)d_in[0];
  const float* r_cos = (const float*)d_in[1];
  const float* r_sin = (const float*)d_in[2];
  const float* wnorm = (const float*)d_in[3];
  const float* wq    = (const float*)d_in[4];
  const float* wk    = (const float*)d_in[5];
  const float* wv    = (const float*)d_in[6];
  const float* wo    = (const float*)d_in[7];

  // ws layout (bf16 elems): bufA 8.39M | qkvb 10.49M | wT 25.17M | vtg 2.10M = 92.3MB
  unsigned short* bufA = (unsigned short*)d_ws;                  // h, later attn-out
  unsigned short* qkvb = bufA + (size_t)TOK * DMODEL;            // [2048][5120]
  unsigned short* wT   = qkvb + (size_t)TOK * QKV_LD;            // wqkv^T, later wo^T
  unsigned short* vtg  = wT + (size_t)6144 * DMODEL;             // V^T [1024][2048]

  // dynamic-LDS caps (idempotent, host-side; safe under graph capture)
  hipFuncSetAttribute((const void*)k_gemm_big<256, 192, 0, 3>,
                      hipFuncAttributeMaxDynamicSharedMemorySize, 4 * (256 + 192) * 64);
  hipFuncSetAttribute((const void*)k_gemm_big<128, 256, 1, 2>,
                      hipFuncAttributeMaxDynamicSharedMemorySize, 4 * (128 + 256) * 64);
  const int attn_lds = 4 * KVB * 128 * 2 + 4 * 16 * PS_LD * 2;   // 74752 B
  hipFuncSetAttribute((const void*)k_attn,
                      hipFuncAttributeMaxDynamicSharedMemorySize, attn_lds);

  k_rmsnorm<<<TOK, 256, 0, stream>>>(x, wnorm, bufA);
  k_wconvert<<<dim3(64, 64), 256, 0, stream>>>(wq, wT, DMODEL, 4096);
  k_wconvert<<<dim3(16, 64), 256, 0, stream>>>(wk, wT + (size_t)4096 * DMODEL, DMODEL, 1024);
  k_wconvert<<<dim3(16, 64), 256, 0, stream>>>(wv, wT + (size_t)5120 * DMODEL, DMODEL, 1024);
  k_gemm_big<256, 192, 0, 3><<<dim3(256), 512, 4 * (256 + 192) * 64, stream>>>(
      bufA, wT, nullptr, qkvb, vtg, r_cos, r_sin, TOK, 6144, DMODEL);
  k_wconvert<<<dim3(64, 64), 256, 0, stream>>>(wo, wT, DMODEL, 4096);   // overlay: wo^T
  k_attn<<<dim3(16, 32), 256, attn_lds, stream>>>(qkvb, vtg, bufA);
  k_gemm_big<128, 256, 1, 2><<<dim3(256), 512, 4 * (128 + 256) * 64, stream>>>(
      bufA, wT, x, d_out, nullptr, nullptr, nullptr, TOK, DMODEL, DMODEL);
}